// Round 11
// baseline (826.395 us; speedup 1.0000x reference)
//
#include <hip/hip_runtime.h>
#include <hip/hip_bf16.h>

typedef __hip_bfloat16 bf16;
typedef unsigned int uint;
typedef unsigned short ushort;

#define N_NODES 100000
#define N_EDGES_C 1600000
#define NSB 196            // super-buckets: dst>>9 (512 dsts each); 196*512=100352
#define NSBP 200           // padded counter array size
#define SBCAP 10240        // per-SB region capacity (mean 8163, +23 sigma)
#define RND 4096           // edges per radix_a block

// ---------- runtime dtype helpers (flags[0]=floats-are-bf16, flags[1]=indices-are-int64) ----------
__device__ __forceinline__ float ldf(const void* p, long i, int isbf) {
    return isbf ? __bfloat162float(((const bf16*)p)[i]) : ((const float*)p)[i];
}
__device__ __forceinline__ int ldidx(const int* ei, long pos, int is64) {
    return is64 ? ei[2 * pos] : ei[pos];   // int64 LE: low word at 2*pos
}
__device__ __forceinline__ ushort bfb(float x) {   // f32 -> bf16 bits (RNE)
    bf16 h = __float2bfloat16(x);
    return *(ushort*)&h;
}
__device__ __forceinline__ float bl(uint u) { return __uint_as_float(u << 16); }        // low bf16
__device__ __forceinline__ float bh(uint u) { return __uint_as_float(u & 0xFFFF0000u); } // high bf16

// ---------- dtype detection ----------
__global__ void detect_kernel(const void* emb, const int* ei, int* flags) {
    if (blockIdx.x == 0 && threadIdx.x == 0) {
        const bf16* pb = (const bf16*)emb;
        int big = 0;
        for (int i = 0; i < 256; i++) {
            float v = __bfloat162float(pb[i]);
            if (!(v > -1.0e6f && v < 1.0e6f)) big++;  // f32-viewed-as-bf16 => ~42% huge/nan
        }
        flags[0] = (big <= 8) ? 1 : 0;
        int nz = 0;
        for (int i = 1; i < 256; i += 2) nz += (ei[i] != 0) ? 1 : 0;
        flags[1] = (nz == 0) ? 1 : 0;     // int64 => odd int32 words all zero
    }
}

__global__ void cast_params(
    const void* Wq1, const void* bq1, const void* Wk1, const void* bk1,
    const void* Wv1, const void* bv1, const void* Ws1, const void* bs1,
    const void* Wq2, const void* bq2, const void* Wk2, const void* bk2,
    const void* Wv2, const void* bv2, const void* Ws2, const void* bs2,
    const void* Wo, const void* bo, const int* __restrict__ flags,
    float* __restrict__ wp1, float* __restrict__ bp1,
    float* __restrict__ wp2, float* __restrict__ bp2, float* __restrict__ woF) {
    int isbf = flags[0];
    int t = threadIdx.x;
    for (int i = t; i < 1024; i += 256) {
        wp1[i]        = ldf(Wq1, i, isbf);
        wp1[1024 + i] = ldf(Wk1, i, isbf);
        wp1[2048 + i] = ldf(Wv1, i, isbf);
        wp1[3072 + i] = ldf(Ws1, i, isbf);
    }
    for (int i = t; i < 512; i += 256) {
        wp2[i]        = ldf(Wq2, i, isbf);
        wp2[512 + i]  = ldf(Wk2, i, isbf);
        wp2[1024 + i] = ldf(Wv2, i, isbf);
        wp2[1536 + i] = ldf(Ws2, i, isbf);
    }
    if (t < 32) {
        bp1[t] = ldf(bq1, t, isbf); bp1[32 + t] = ldf(bk1, t, isbf);
        bp1[64 + t] = ldf(bv1, t, isbf); bp1[96 + t] = ldf(bs1, t, isbf);
        woF[t] = ldf(Wo, t, isbf);
    }
    if (t < 16) {
        bp2[t] = ldf(bq2, t, isbf); bp2[16 + t] = ldf(bk2, t, isbf);
        bp2[32 + t] = ldf(bv2, t, isbf); bp2[48 + t] = ldf(bs2, t, isbf);
    }
    if (t < 2) woF[32 + t] = ldf(bo, t, isbf);
}

__global__ void zero_i(int* __restrict__ p, int n) {
    int i = blockIdx.x * blockDim.x + threadIdx.x;
    if (i < n) p[i] = 0;
}

// ---------- Pass A: LDS-coalesced radix into 196 super-buckets ----------
__global__ void radix_a(const int* __restrict__ ei, const int* __restrict__ flags,
                        int* __restrict__ curSB, uint* __restrict__ pairsSB) {
    __shared__ int cnt[NSBP];
    __shared__ int excl[NSBP];
    __shared__ int gbase[NSBP];
    __shared__ uint sVal[RND];
    __shared__ unsigned char sSb[RND];
    const int is64 = flags[1];
    int t = threadIdx.x;
    for (int i = t; i < NSBP; i += 256) cnt[i] = 0;
    __syncthreads();
    long base = (long)blockIdx.x * RND;

    int mySb[16]; int myRank[16]; uint myPk[16];
#pragma unroll
    for (int r = 0; r < 16; r++) {
        long e = base + r * 256 + t;
        mySb[r] = -1;
        if (e < N_EDGES_C) {
            int d = ldidx(ei, (long)N_EDGES_C + e, is64);
            int s = ldidx(ei, e, is64);
            int sb = d >> 9;
            myPk[r] = (uint)s | ((uint)(d & 511) << 17);
            myRank[r] = atomicAdd(&cnt[sb], 1);
            mySb[r] = sb;
        }
    }
    __syncthreads();
    if (t == 0) {
        int o = 0;
        for (int i = 0; i < NSBP; i++) { excl[i] = o; o += cnt[i]; }
    }
    __syncthreads();
#pragma unroll
    for (int r = 0; r < 16; r++) {
        if (mySb[r] >= 0) {
            int pos = excl[mySb[r]] + myRank[r];
            sVal[pos] = myPk[r];
            sSb[pos] = (unsigned char)mySb[r];
        }
    }
    __syncthreads();
    for (int i = t; i < NSBP; i += 256)
        gbase[i] = (cnt[i] > 0) ? atomicAdd(&curSB[i], cnt[i]) : 0;
    __syncthreads();
    int tot = excl[NSBP - 1] + cnt[NSBP - 1];
    for (int i = t; i < tot; i += 256) {   // consecutive i in a run -> consecutive global addr
        int sb = sSb[i];
        int gp = gbase[sb] + (i - excl[sb]);
        if (gp < SBCAP)
            pairsSB[(size_t)sb * SBCAP + gp] = sVal[i];
    }
}

// ---------- Pass B: per-SB CSR build (512 dsts) ----------
__global__ void radix_b(const int* __restrict__ curSB, const uint* __restrict__ pairsSB,
                        int* __restrict__ esrc,
                        int* __restrict__ rowbeg, int* __restrict__ rowend) {
    __shared__ uint sP[SBCAP];                 // 40 KB
    __shared__ int dcnt[512], dexcl[512], dcur[512];
    int sb = blockIdx.x;
    int t = threadIdx.x;
    int n = min(curSB[sb], SBCAP);
    for (int i = t; i < 512; i += 256) { dcnt[i] = 0; dcur[i] = 0; }
    __syncthreads();
    for (int i = t; i < n; i += 256) {
        uint pk = pairsSB[(size_t)sb * SBCAP + i];
        sP[i] = pk;
        atomicAdd(&dcnt[(pk >> 17) & 511], 1);
    }
    __syncthreads();
    if (t == 0) {
        int o = 0;
        for (int j = 0; j < 512; j++) { dexcl[j] = o; o += dcnt[j]; }
    }
    __syncthreads();
    const int EB = sb * SBCAP;
    for (int j = t; j < 512; j += 256) {
        int dst = sb * 512 + j;
        if (dst < N_NODES) {
            rowbeg[dst] = EB + dexcl[j];
            rowend[dst] = EB + dexcl[j] + dcnt[j];
        }
    }
    for (int i = t; i < n; i += 256) {
        uint pk = sP[i];
        int j = (pk >> 17) & 511;
        int p = dexcl[j] + atomicAdd(&dcur[j], 1);
        esrc[EB + p] = (int)(pk & 0x1FFFF);
    }
}

// ---------- degree-sorted dst permutation (counting sort, 256 bins) ----------
// Groups within a gather wave then have ~equal degree -> no lockstep divergence.
__global__ void deg_hist(const int* __restrict__ rowbeg, const int* __restrict__ rowend,
                         int* __restrict__ hist) {
    int i = blockIdx.x * blockDim.x + threadIdx.x;
    if (i >= N_NODES) return;
    int d = min(rowend[i] - rowbeg[i], 255);
    atomicAdd(&hist[d], 1);
}

__global__ void hist_scan(const int* __restrict__ hist, int* __restrict__ offs) {
    __shared__ int tmp[256];
    int v = hist[threadIdx.x];
    tmp[threadIdx.x] = v;
    __syncthreads();
    for (int off = 1; off < 256; off <<= 1) {
        int t = (threadIdx.x >= off) ? tmp[threadIdx.x - off] : 0;
        __syncthreads();
        tmp[threadIdx.x] += t;
        __syncthreads();
    }
    offs[threadIdx.x] = tmp[threadIdx.x] - v;  // exclusive
}

__global__ void perm_scatter(const int* __restrict__ rowbeg, const int* __restrict__ rowend,
                             int* __restrict__ offs, int* __restrict__ perm) {
    int i = blockIdx.x * blockDim.x + threadIdx.x;
    if (i >= N_NODES) return;
    int d = min(rowend[i] - rowbeg[i], 255);
    int pos = atomicAdd(&offs[d], 1);
    perm[pos] = i;
}

// ---------- node linears (gated dtype variants; kv packed bf16 out) ----------
// wantbf>=0: block runs only if flags[0]==wantbf (cheap uniform early-exit).
template <int DOUT, bool XBF16>
__global__ void node_linear(const void* __restrict__ X,       // [N,32] bf16 or f32
                            const float* __restrict__ wpack,  // [4][32][DOUT] f32
                            const float* __restrict__ bpack,  // [4][DOUT] f32
                            const int* __restrict__ flags, int wantbf,
                            float* __restrict__ q, ushort* __restrict__ kvb,
                            float* __restrict__ s) {
    if (wantbf >= 0 && flags[0] != wantbf) return;
    const int TPN = DOUT / 4;     // threads per node (8 or 4)
    const int NPB = 256 / TPN;    // nodes per block (32 or 64)
    const int W_ELEMS = 4 * 32 * DOUT;
    __shared__ float sW[W_ELEMS];
    __shared__ float sb[4 * DOUT];
    __shared__ float sX[NPB * 36];  // pad stride 36 (16B-aligned, conflict-free)

    const float4* wp4 = (const float4*)wpack;
    float4* sW4 = (float4*)sW;
    for (int i = threadIdx.x; i < W_ELEMS / 4; i += 256) sW4[i] = wp4[i];
    if (threadIdx.x < 4 * DOUT) sb[threadIdx.x] = bpack[threadIdx.x];
    const int base = blockIdx.x * NPB * 32;
    for (int i = threadIdx.x; i < NPB * 32; i += 256) {
        int g = base + i;
        float xv = 0.0f;
        if (g < N_NODES * 32)
            xv = XBF16 ? __bfloat162float(((const bf16*)X)[g]) : ((const float*)X)[g];
        sX[(i >> 5) * 36 + (i & 31)] = xv;
    }
    __syncthreads();

    int l = threadIdx.x / TPN;
    int c4 = (threadIdx.x % TPN) * 4;
    int n = blockIdx.x * NPB + l;
    if (n >= N_NODES) return;

    float xr[32];
#pragma unroll
    for (int j = 0; j < 8; j++) {
        float4 t = *(const float4*)&sX[l * 36 + 4 * j];
        xr[4 * j] = t.x; xr[4 * j + 1] = t.y; xr[4 * j + 2] = t.z; xr[4 * j + 3] = t.w;
    }
    float acc[4][4];
#pragma unroll
    for (int m = 0; m < 4; m++)
#pragma unroll
        for (int j = 0; j < 4; j++) acc[m][j] = sb[m * DOUT + c4 + j];

#pragma unroll
    for (int t = 0; t < 32; t++) {
#pragma unroll
        for (int m = 0; m < 4; m++) {
            float4 w = *(const float4*)&sW[(m * 32 + t) * DOUT + c4];
            acc[m][0] += xr[t] * w.x;
            acc[m][1] += xr[t] * w.y;
            acc[m][2] += xr[t] * w.z;
            acc[m][3] += xr[t] * w.w;
        }
    }
    size_t o = (size_t)n * DOUT + c4;
    *(float4*)&q[o] = make_float4(acc[0][0], acc[0][1], acc[0][2], acc[0][3]);
    *(float4*)&s[o] = make_float4(acc[3][0], acc[3][1], acc[3][2], acc[3][3]);
    size_t okv = (size_t)n * 2 * DOUT + c4;
    ushort4 kp = make_ushort4(bfb(acc[1][0]), bfb(acc[1][1]), bfb(acc[1][2]), bfb(acc[1][3]));
    ushort4 vp = make_ushort4(bfb(acc[2][0]), bfb(acc[2][1]), bfb(acc[2][2]), bfb(acc[2][3]));
    *(ushort4*)&kvb[okv]        = kp;
    *(ushort4*)&kvb[okv + DOUT] = vp;
}

// ---------- fused gather attention (bf16 kv, D/2 lanes per dst, degree-sorted) ----------
template <int D, bool LAYER2>
__global__ void gather_attn(const int* __restrict__ perm,
                            const int* __restrict__ rowbeg, const int* __restrict__ rowend,
                            const int* __restrict__ esrc,
                            const float* __restrict__ q, const ushort* __restrict__ kvb,
                            const float* __restrict__ s,
                            const float* __restrict__ woF,  // [32]=Wo, [32..33]=bo (f32)
                            const int* __restrict__ flags,
                            float* __restrict__ h1o, void* __restrict__ out) {
    const int LPD = D / 2;   // lanes per dst (16 or 8)
    const int G = 64 / LPD;  // dst groups per wave (4 or 8)
    int lane = threadIdx.x & 63;
    int wave = (blockIdx.x * blockDim.x + threadIdx.x) >> 6;
    int g = lane / LPD;
    int c = lane % LPD;      // dims 2c, 2c+1
    int idx = wave * G + g;
    if (idx >= N_NODES) return;  // uniform within a group; shfl stays in-group
    int dst = perm[idx];         // degree-sorted: all groups in wave have ~equal degree

    const float rsq = (D == 32) ? 0.17677669529663689f : 0.25f;  // 1/sqrt(D)
    float2 qc = *(const float2*)(q + (size_t)dst * D + 2 * c);
    int beg = rowbeg[dst], end = rowend[dst];

    const char* kvbase = (const char*)kvb;
    const int ROW = 4 * D;            // row bytes: [k bf16 x D | v bf16 x D]
    const int koff = 4 * c;
    const int voff = 2 * D + 4 * c;

    float sum0 = 0.f, sum1 = 0.f;
    float a00 = 0.f, a01 = 0.f, a10 = 0.f, a11 = 0.f;

    // 2-deep software pipeline, unroll x2
    int sn0 = (beg < end) ? esrc[beg] : 0;
    int sn1 = (beg + 1 < end) ? esrc[beg + 1] : 0;
    const char* pa = kvbase + (size_t)sn0 * ROW;
    const char* pb = kvbase + (size_t)sn1 * ROW;
    uint kau = *(const uint*)(pa + koff), vau = *(const uint*)(pa + voff);
    uint kbu = *(const uint*)(pb + koff), vbu = *(const uint*)(pb + voff);

    for (int e = beg; e < end; e += 2) {
        uint kA = kau, vA = vau, kB = kbu, vB = vbu;
        if (e + 2 < end) {
            const char* p = kvbase + (size_t)esrc[e + 2] * ROW;
            kau = *(const uint*)(p + koff); vau = *(const uint*)(p + voff);
        }
        if (e + 3 < end) {
            const char* p = kvbase + (size_t)esrc[e + 3] * ROW;
            kbu = *(const uint*)(p + koff); vbu = *(const uint*)(p + voff);
        }
        float pd = qc.x * bl(kA) + qc.y * bh(kA);
#pragma unroll
        for (int m = LPD / 2; m >= 1; m >>= 1) pd += __shfl_xor(pd, m, LPD);
        float ex = __expf(fminf(fmaxf(pd * rsq, -80.0f), 80.0f));
        sum0 += ex; a00 += bl(vA) * ex; a01 += bh(vA) * ex;
        if (e + 1 < end) {
            float pd1 = qc.x * bl(kB) + qc.y * bh(kB);
#pragma unroll
            for (int m = LPD / 2; m >= 1; m >>= 1) pd1 += __shfl_xor(pd1, m, LPD);
            float ex1 = __expf(fminf(fmaxf(pd1 * rsq, -80.0f), 80.0f));
            sum1 += ex1; a10 += bl(vB) * ex1; a11 += bh(vB) * ex1;
        }
    }
    float inv = 1.0f / (sum0 + sum1 + 1e-16f);
    float2 sc = *(const float2*)(s + (size_t)dst * D + 2 * c);
    float h0 = (a00 + a10) * inv + sc.x; h0 = h0 > 0.0f ? h0 : 0.0f;
    float h1 = (a01 + a11) * inv + sc.y; h1 = h1 > 0.0f ? h1 : 0.0f;

    if (!LAYER2) {
        *(float2*)(h1o + (size_t)dst * D + 2 * c) = make_float2(h0, h1);
    } else {
        float p0 = h0 * woF[4 * c + 0] + h1 * woF[4 * c + 2];
        float p1 = h0 * woF[4 * c + 1] + h1 * woF[4 * c + 3];
#pragma unroll
        for (int m = LPD / 2; m >= 1; m >>= 1) {
            p0 += __shfl_xor(p0, m, LPD);
            p1 += __shfl_xor(p1, m, LPD);
        }
        if (c == 0) {
            float o0 = p0 + woF[32];
            float o1 = p1 + woF[33];
            if (flags[0]) {
                ((bf16*)out)[dst * 2 + 0] = __float2bfloat16(o0);
                ((bf16*)out)[dst * 2 + 1] = __float2bfloat16(o1);
            } else {
                ((float*)out)[dst * 2 + 0] = o0;
                ((float*)out)[dst * 2 + 1] = o1;
            }
        }
    }
}

extern "C" void kernel_launch(void* const* d_in, const int* in_sizes, int n_in,
                              void* d_out, int out_size, void* d_ws, size_t ws_size,
                              hipStream_t stream) {
    const int* ei  = (const int*)d_in[0];
    const void* emb = d_in[1];
    const void *Wq1 = d_in[2],  *bq1 = d_in[3];
    const void *Wk1 = d_in[4],  *bk1 = d_in[5];
    const void *Wv1 = d_in[6],  *bv1 = d_in[7];
    const void *Ws1 = d_in[8],  *bs1 = d_in[9];
    const void *Wq2 = d_in[10], *bq2 = d_in[11];
    const void *Wk2 = d_in[12], *bk2 = d_in[13];
    const void *Wv2 = d_in[14], *bv2 = d_in[15];
    const void *Ws2 = d_in[16], *bs2 = d_in[17];
    const void *Wo  = d_in[18], *bo  = d_in[19];

    // Workspace layout (floats). pairsSB aliases q (dead after radix_b).
    const size_t ND = (size_t)N_NODES * 32;
    const size_t SBTOT = (size_t)NSB * SBCAP;      // 2,007,040
    float* base   = (float*)d_ws;
    int*   flags  = (int*)base;                    // 64
    float* wp1    = base + 64;                     // 4096
    float* bp1    = wp1 + 4096;                    // 128
    float* wp2    = bp1 + 128;                     // 2048
    float* bp2    = wp2 + 2048;                    // 64
    float* woF    = bp2 + 64;                      // 64
    int*   curSB  = (int*)(woF + 64);              // 256
    int*   hist   = curSB + 256;                   // 256 (zeroed together with curSB)
    int*   offs   = hist + 256;                    // 256
    int*   rowbeg = offs + 256;                    // N_NODES
    int*   rowend = rowbeg + N_NODES;              // N_NODES
    int*   perm   = rowend + N_NODES;              // N_NODES
    float* uni    = (float*)(perm + N_NODES);      // union start
    uint*  pairsSB = (uint*)uni;                   // SBTOT uints (8 MB, alias q)
    float* q      = uni;                           // ND
    float* s      = uni + ND;                      // ND
    ushort* kvb   = (ushort*)(uni + 2 * ND);       // 2*ND ushorts = ND floats
    float* h1     = uni + 3 * ND;                  // ND
    int*   esrc   = (int*)(uni + 4 * ND);          // SBTOT ints (8 MB)
    // total ~ 61 MB

    const int B = 256;
    const int gNode   = (N_NODES + B - 1) / B;         // 391
    const int gNL32   = (N_NODES + 31) / 32;           // 3125 (NPB=32)
    const int gNL16   = (N_NODES + 63) / 64;           // 1563 (NPB=64)
    const int gGat32  = ((N_NODES + 3) / 4 * 64 + B - 1) / B;   // 6250
    const int gGat16  = ((N_NODES + 7) / 8 * 64 + B - 1) / B;   // 3125
    const int gRadA   = (N_EDGES_C + RND - 1) / RND;   // 391

    detect_kernel<<<1, 64, 0, stream>>>(emb, ei, flags);
    cast_params<<<1, B, 0, stream>>>(Wq1, bq1, Wk1, bk1, Wv1, bv1, Ws1, bs1,
                                     Wq2, bq2, Wk2, bk2, Wv2, bv2, Ws2, bs2,
                                     Wo, bo, flags, wp1, bp1, wp2, bp2, woF);

    // ---- CSR build via LDS-coalesced 2-level radix ----
    zero_i<<<2, B, 0, stream>>>(curSB, 512);           // curSB + hist
    radix_a<<<gRadA, B, 0, stream>>>(ei, flags, curSB, pairsSB);
    radix_b<<<NSB, B, 0, stream>>>(curSB, pairsSB, esrc, rowbeg, rowend);

    // ---- degree-sorted dst permutation ----
    deg_hist<<<gNode, B, 0, stream>>>(rowbeg, rowend, hist);
    hist_scan<<<1, 256, 0, stream>>>(hist, offs);
    perm_scatter<<<gNode, B, 0, stream>>>(rowbeg, rowend, offs, perm);

    // ---- Layer 1 (32 -> 32): dual gated variants, no separate cast ----
    node_linear<32, true ><<<gNL32, B, 0, stream>>>(emb, wp1, bp1, flags, 1, q, kvb, s);
    node_linear<32, false><<<gNL32, B, 0, stream>>>(emb, wp1, bp1, flags, 0, q, kvb, s);
    gather_attn<32, false><<<gGat32, B, 0, stream>>>(
        perm, rowbeg, rowend, esrc, q, kvb, s, woF, flags, h1, nullptr);

    // ---- Layer 2 (32 -> 16) + output linear ----
    node_linear<16, false><<<gNL16, B, 0, stream>>>(h1, wp2, bp2, flags, -1, q, kvb, s);
    gather_attn<16, true><<<gGat16, B, 0, stream>>>(
        perm, rowbeg, rowend, esrc, q, kvb, s, woF, flags, nullptr, d_out);
}

// Round 12
// 311.608 us; speedup vs baseline: 2.6520x; 2.6520x over previous
//
#include <hip/hip_runtime.h>
#include <hip/hip_bf16.h>

typedef __hip_bfloat16 bf16;
typedef unsigned int uint;
typedef unsigned short ushort;

#define N_NODES 100000
#define N_EDGES_C 1600000
#define NSB 196            // super-buckets: dst>>9 (512 dsts each); 196*512=100352
#define NSBP 200           // padded counter array size
#define SBCAP 10240        // per-SB region capacity (mean 8163, +23 sigma)
#define RND 4096           // edges per radix_a block
#define NBLKH 391          // perm-sort blocks: ceil(100000/256)
#define PN (256 * NBLKH)   // flattened (bin-major) count array: 100,096
#define PCH 196            // scan chunks of 512: ceil(PN/512)

// ---------- runtime dtype helpers (flags[0]=floats-are-bf16, flags[1]=indices-are-int64) ----------
__device__ __forceinline__ float ldf(const void* p, long i, int isbf) {
    return isbf ? __bfloat162float(((const bf16*)p)[i]) : ((const float*)p)[i];
}
__device__ __forceinline__ int ldidx(const int* ei, long pos, int is64) {
    return is64 ? ei[2 * pos] : ei[pos];   // int64 LE: low word at 2*pos
}
__device__ __forceinline__ ushort bfb(float x) {   // f32 -> bf16 bits (RNE)
    bf16 h = __float2bfloat16(x);
    return *(ushort*)&h;
}
__device__ __forceinline__ float bl(uint u) { return __uint_as_float(u << 16); }        // low bf16
__device__ __forceinline__ float bh(uint u) { return __uint_as_float(u & 0xFFFF0000u); } // high bf16

// ---------- dtype detection ----------
__global__ void detect_kernel(const void* emb, const int* ei, int* flags) {
    if (blockIdx.x == 0 && threadIdx.x == 0) {
        const bf16* pb = (const bf16*)emb;
        int big = 0;
        for (int i = 0; i < 256; i++) {
            float v = __bfloat162float(pb[i]);
            if (!(v > -1.0e6f && v < 1.0e6f)) big++;  // f32-viewed-as-bf16 => ~42% huge/nan
        }
        flags[0] = (big <= 8) ? 1 : 0;
        int nz = 0;
        for (int i = 1; i < 256; i += 2) nz += (ei[i] != 0) ? 1 : 0;
        flags[1] = (nz == 0) ? 1 : 0;     // int64 => odd int32 words all zero
    }
}

__global__ void cast_params(
    const void* Wq1, const void* bq1, const void* Wk1, const void* bk1,
    const void* Wv1, const void* bv1, const void* Ws1, const void* bs1,
    const void* Wq2, const void* bq2, const void* Wk2, const void* bk2,
    const void* Wv2, const void* bv2, const void* Ws2, const void* bs2,
    const void* Wo, const void* bo, const int* __restrict__ flags,
    float* __restrict__ wp1, float* __restrict__ bp1,
    float* __restrict__ wp2, float* __restrict__ bp2, float* __restrict__ woF) {
    int isbf = flags[0];
    int t = threadIdx.x;
    for (int i = t; i < 1024; i += 256) {
        wp1[i]        = ldf(Wq1, i, isbf);
        wp1[1024 + i] = ldf(Wk1, i, isbf);
        wp1[2048 + i] = ldf(Wv1, i, isbf);
        wp1[3072 + i] = ldf(Ws1, i, isbf);
    }
    for (int i = t; i < 512; i += 256) {
        wp2[i]        = ldf(Wq2, i, isbf);
        wp2[512 + i]  = ldf(Wk2, i, isbf);
        wp2[1024 + i] = ldf(Wv2, i, isbf);
        wp2[1536 + i] = ldf(Ws2, i, isbf);
    }
    if (t < 32) {
        bp1[t] = ldf(bq1, t, isbf); bp1[32 + t] = ldf(bk1, t, isbf);
        bp1[64 + t] = ldf(bv1, t, isbf); bp1[96 + t] = ldf(bs1, t, isbf);
        woF[t] = ldf(Wo, t, isbf);
    }
    if (t < 16) {
        bp2[t] = ldf(bq2, t, isbf); bp2[16 + t] = ldf(bk2, t, isbf);
        bp2[32 + t] = ldf(bv2, t, isbf); bp2[48 + t] = ldf(bs2, t, isbf);
    }
    if (t < 2) woF[32 + t] = ldf(bo, t, isbf);
}

__global__ void zero_i(int* __restrict__ p, int n) {
    int i = blockIdx.x * blockDim.x + threadIdx.x;
    if (i < n) p[i] = 0;
}

// ---------- Pass A: LDS-coalesced radix into 196 super-buckets ----------
__global__ void radix_a(const int* __restrict__ ei, const int* __restrict__ flags,
                        int* __restrict__ curSB, uint* __restrict__ pairsSB) {
    __shared__ int cnt[NSBP];
    __shared__ int excl[NSBP];
    __shared__ int gbase[NSBP];
    __shared__ uint sVal[RND];
    __shared__ unsigned char sSb[RND];
    const int is64 = flags[1];
    int t = threadIdx.x;
    for (int i = t; i < NSBP; i += 256) cnt[i] = 0;
    __syncthreads();
    long base = (long)blockIdx.x * RND;

    int mySb[16]; int myRank[16]; uint myPk[16];
#pragma unroll
    for (int r = 0; r < 16; r++) {
        long e = base + r * 256 + t;
        mySb[r] = -1;
        if (e < N_EDGES_C) {
            int d = ldidx(ei, (long)N_EDGES_C + e, is64);
            int s = ldidx(ei, e, is64);
            int sb = d >> 9;
            myPk[r] = (uint)s | ((uint)(d & 511) << 17);
            myRank[r] = atomicAdd(&cnt[sb], 1);
            mySb[r] = sb;
        }
    }
    __syncthreads();
    if (t == 0) {
        int o = 0;
        for (int i = 0; i < NSBP; i++) { excl[i] = o; o += cnt[i]; }
    }
    __syncthreads();
#pragma unroll
    for (int r = 0; r < 16; r++) {
        if (mySb[r] >= 0) {
            int pos = excl[mySb[r]] + myRank[r];
            sVal[pos] = myPk[r];
            sSb[pos] = (unsigned char)mySb[r];
        }
    }
    __syncthreads();
    for (int i = t; i < NSBP; i += 256)
        gbase[i] = (cnt[i] > 0) ? atomicAdd(&curSB[i], cnt[i]) : 0;
    __syncthreads();
    int tot = excl[NSBP - 1] + cnt[NSBP - 1];
    for (int i = t; i < tot; i += 256) {   // consecutive i in a run -> consecutive global addr
        int sb = sSb[i];
        int gp = gbase[sb] + (i - excl[sb]);
        if (gp < SBCAP)
            pairsSB[(size_t)sb * SBCAP + gp] = sVal[i];
    }
}

// ---------- Pass B: per-SB CSR build (512 dsts) ----------
__global__ void radix_b(const int* __restrict__ curSB, const uint* __restrict__ pairsSB,
                        int* __restrict__ esrc,
                        int* __restrict__ rowbeg, int* __restrict__ rowend) {
    __shared__ uint sP[SBCAP];                 // 40 KB
    __shared__ int dcnt[512], dexcl[512], dcur[512];
    int sb = blockIdx.x;
    int t = threadIdx.x;
    int n = min(curSB[sb], SBCAP);
    for (int i = t; i < 512; i += 256) { dcnt[i] = 0; dcur[i] = 0; }
    __syncthreads();
    for (int i = t; i < n; i += 256) {
        uint pk = pairsSB[(size_t)sb * SBCAP + i];
        sP[i] = pk;
        atomicAdd(&dcnt[(pk >> 17) & 511], 1);
    }
    __syncthreads();
    if (t == 0) {
        int o = 0;
        for (int j = 0; j < 512; j++) { dexcl[j] = o; o += dcnt[j]; }
    }
    __syncthreads();
    const int EB = sb * SBCAP;
    for (int j = t; j < 512; j += 256) {
        int dst = sb * 512 + j;
        if (dst < N_NODES) {
            rowbeg[dst] = EB + dexcl[j];
            rowend[dst] = EB + dexcl[j] + dcnt[j];
        }
    }
    for (int i = t; i < n; i += 256) {
        uint pk = sP[i];
        int j = (pk >> 17) & 511;
        int p = dexcl[j] + atomicAdd(&dcur[j], 1);
        esrc[EB + p] = (int)(pk & 0x1FFFF);
    }
}

// ---------- degree-sorted dst permutation (contention-free counting sort) ----------
// Phase 1: per-block LDS histogram -> cnt[bin][block] (bin-major, NO global atomics).
__global__ void deg_cnt(const int* __restrict__ rowbeg, const int* __restrict__ rowend,
                        int* __restrict__ cnt) {
    __shared__ int h[256];
    int t = threadIdx.x, b = blockIdx.x;
    h[t] = 0;
    __syncthreads();
    int i = b * 256 + t;
    if (i < N_NODES) {
        int d = min(rowend[i] - rowbeg[i], 255);
        atomicAdd(&h[d], 1);            // LDS atomic, ~26 per bin per block
    }
    __syncthreads();
    cnt[t * NBLKH + b] = h[t];
}

// Phase 2: hierarchical exclusive scan over flattened bin-major array (PN entries).
__global__ void scan_chunk2(const int* __restrict__ x, int* __restrict__ y,
                            int* __restrict__ csums) {
    __shared__ int tmp[512];
    int i = blockIdx.x * 512 + threadIdx.x;
    int v = (i < PN) ? x[i] : 0;
    tmp[threadIdx.x] = v;
    __syncthreads();
    for (int off = 1; off < 512; off <<= 1) {
        int t = (threadIdx.x >= off) ? tmp[threadIdx.x - off] : 0;
        __syncthreads();
        tmp[threadIdx.x] += t;
        __syncthreads();
    }
    if (i < PN) y[i] = tmp[threadIdx.x] - v;  // exclusive
    if (threadIdx.x == 511) csums[blockIdx.x] = tmp[threadIdx.x];
}

__global__ void scan_sums2(int* __restrict__ csums, int* __restrict__ coffs) {
    __shared__ int tmp[256];
    int v = (threadIdx.x < PCH) ? csums[threadIdx.x] : 0;
    tmp[threadIdx.x] = v;
    __syncthreads();
    for (int off = 1; off < 256; off <<= 1) {
        int t = (threadIdx.x >= off) ? tmp[threadIdx.x - off] : 0;
        __syncthreads();
        tmp[threadIdx.x] += t;
        __syncthreads();
    }
    if (threadIdx.x < PCH) coffs[threadIdx.x] = tmp[threadIdx.x] - v;
}

__global__ void add_offs2(int* __restrict__ y, const int* __restrict__ coffs) {
    int i = blockIdx.x * blockDim.x + threadIdx.x;
    if (i < PN) y[i] += coffs[i / 512];
}

// Phase 3: scatter with LDS-local rank; per-(bin,block) output runs are contiguous.
__global__ void perm_scatter2(const int* __restrict__ rowbeg, const int* __restrict__ rowend,
                              const int* __restrict__ basearr, int* __restrict__ perm) {
    __shared__ int cur[256];
    int t = threadIdx.x, b = blockIdx.x;
    cur[t] = 0;
    __syncthreads();
    int i = b * 256 + t;
    if (i < N_NODES) {
        int d = min(rowend[i] - rowbeg[i], 255);
        int r = atomicAdd(&cur[d], 1);  // LDS atomic
        perm[basearr[d * NBLKH + b] + r] = i;
    }
}

// ---------- node linears (gated dtype variants; kv packed bf16 out) ----------
template <int DOUT, bool XBF16>
__global__ void node_linear(const void* __restrict__ X,       // [N,32] bf16 or f32
                            const float* __restrict__ wpack,  // [4][32][DOUT] f32
                            const float* __restrict__ bpack,  // [4][DOUT] f32
                            const int* __restrict__ flags, int wantbf,
                            float* __restrict__ q, ushort* __restrict__ kvb,
                            float* __restrict__ s) {
    if (wantbf >= 0 && flags[0] != wantbf) return;
    const int TPN = DOUT / 4;     // threads per node (8 or 4)
    const int NPB = 256 / TPN;    // nodes per block (32 or 64)
    const int W_ELEMS = 4 * 32 * DOUT;
    __shared__ float sW[W_ELEMS];
    __shared__ float sb[4 * DOUT];
    __shared__ float sX[NPB * 36];  // pad stride 36 (16B-aligned, conflict-free)

    const float4* wp4 = (const float4*)wpack;
    float4* sW4 = (float4*)sW;
    for (int i = threadIdx.x; i < W_ELEMS / 4; i += 256) sW4[i] = wp4[i];
    if (threadIdx.x < 4 * DOUT) sb[threadIdx.x] = bpack[threadIdx.x];
    const int base = blockIdx.x * NPB * 32;
    for (int i = threadIdx.x; i < NPB * 32; i += 256) {
        int g = base + i;
        float xv = 0.0f;
        if (g < N_NODES * 32)
            xv = XBF16 ? __bfloat162float(((const bf16*)X)[g]) : ((const float*)X)[g];
        sX[(i >> 5) * 36 + (i & 31)] = xv;
    }
    __syncthreads();

    int l = threadIdx.x / TPN;
    int c4 = (threadIdx.x % TPN) * 4;
    int n = blockIdx.x * NPB + l;
    if (n >= N_NODES) return;

    float xr[32];
#pragma unroll
    for (int j = 0; j < 8; j++) {
        float4 t = *(const float4*)&sX[l * 36 + 4 * j];
        xr[4 * j] = t.x; xr[4 * j + 1] = t.y; xr[4 * j + 2] = t.z; xr[4 * j + 3] = t.w;
    }
    float acc[4][4];
#pragma unroll
    for (int m = 0; m < 4; m++)
#pragma unroll
        for (int j = 0; j < 4; j++) acc[m][j] = sb[m * DOUT + c4 + j];

#pragma unroll
    for (int t = 0; t < 32; t++) {
#pragma unroll
        for (int m = 0; m < 4; m++) {
            float4 w = *(const float4*)&sW[(m * 32 + t) * DOUT + c4];
            acc[m][0] += xr[t] * w.x;
            acc[m][1] += xr[t] * w.y;
            acc[m][2] += xr[t] * w.z;
            acc[m][3] += xr[t] * w.w;
        }
    }
    size_t o = (size_t)n * DOUT + c4;
    *(float4*)&q[o] = make_float4(acc[0][0], acc[0][1], acc[0][2], acc[0][3]);
    *(float4*)&s[o] = make_float4(acc[3][0], acc[3][1], acc[3][2], acc[3][3]);
    size_t okv = (size_t)n * 2 * DOUT + c4;
    ushort4 kp = make_ushort4(bfb(acc[1][0]), bfb(acc[1][1]), bfb(acc[1][2]), bfb(acc[1][3]));
    ushort4 vp = make_ushort4(bfb(acc[2][0]), bfb(acc[2][1]), bfb(acc[2][2]), bfb(acc[2][3]));
    *(ushort4*)&kvb[okv]        = kp;
    *(ushort4*)&kvb[okv + DOUT] = vp;
}

// ---------- fused gather attention (bf16 kv, D/2 lanes per dst, degree-sorted) ----------
template <int D, bool LAYER2>
__global__ void gather_attn(const int* __restrict__ perm,
                            const int* __restrict__ rowbeg, const int* __restrict__ rowend,
                            const int* __restrict__ esrc,
                            const float* __restrict__ q, const ushort* __restrict__ kvb,
                            const float* __restrict__ s,
                            const float* __restrict__ woF,  // [32]=Wo, [32..33]=bo (f32)
                            const int* __restrict__ flags,
                            float* __restrict__ h1o, void* __restrict__ out) {
    const int LPD = D / 2;   // lanes per dst (16 or 8)
    const int G = 64 / LPD;  // dst groups per wave (4 or 8)
    int lane = threadIdx.x & 63;
    int wave = (blockIdx.x * blockDim.x + threadIdx.x) >> 6;
    int g = lane / LPD;
    int c = lane % LPD;      // dims 2c, 2c+1
    int idx = wave * G + g;
    if (idx >= N_NODES) return;  // uniform within a group; shfl stays in-group
    int dst = perm[idx];         // degree-sorted: all groups in wave have ~equal degree

    const float rsq = (D == 32) ? 0.17677669529663689f : 0.25f;  // 1/sqrt(D)
    float2 qc = *(const float2*)(q + (size_t)dst * D + 2 * c);
    int beg = rowbeg[dst], end = rowend[dst];

    const char* kvbase = (const char*)kvb;
    const int ROW = 4 * D;            // row bytes: [k bf16 x D | v bf16 x D]
    const int koff = 4 * c;
    const int voff = 2 * D + 4 * c;

    float sum0 = 0.f, sum1 = 0.f;
    float a00 = 0.f, a01 = 0.f, a10 = 0.f, a11 = 0.f;

    // 2-deep software pipeline, unroll x2
    int sn0 = (beg < end) ? esrc[beg] : 0;
    int sn1 = (beg + 1 < end) ? esrc[beg + 1] : 0;
    const char* pa = kvbase + (size_t)sn0 * ROW;
    const char* pb = kvbase + (size_t)sn1 * ROW;
    uint kau = *(const uint*)(pa + koff), vau = *(const uint*)(pa + voff);
    uint kbu = *(const uint*)(pb + koff), vbu = *(const uint*)(pb + voff);

    for (int e = beg; e < end; e += 2) {
        uint kA = kau, vA = vau, kB = kbu, vB = vbu;
        if (e + 2 < end) {
            const char* p = kvbase + (size_t)esrc[e + 2] * ROW;
            kau = *(const uint*)(p + koff); vau = *(const uint*)(p + voff);
        }
        if (e + 3 < end) {
            const char* p = kvbase + (size_t)esrc[e + 3] * ROW;
            kbu = *(const uint*)(p + koff); vbu = *(const uint*)(p + voff);
        }
        float pd = qc.x * bl(kA) + qc.y * bh(kA);
#pragma unroll
        for (int m = LPD / 2; m >= 1; m >>= 1) pd += __shfl_xor(pd, m, LPD);
        float ex = __expf(fminf(fmaxf(pd * rsq, -80.0f), 80.0f));
        sum0 += ex; a00 += bl(vA) * ex; a01 += bh(vA) * ex;
        if (e + 1 < end) {
            float pd1 = qc.x * bl(kB) + qc.y * bh(kB);
#pragma unroll
            for (int m = LPD / 2; m >= 1; m >>= 1) pd1 += __shfl_xor(pd1, m, LPD);
            float ex1 = __expf(fminf(fmaxf(pd1 * rsq, -80.0f), 80.0f));
            sum1 += ex1; a10 += bl(vB) * ex1; a11 += bh(vB) * ex1;
        }
    }
    float inv = 1.0f / (sum0 + sum1 + 1e-16f);
    float2 sc = *(const float2*)(s + (size_t)dst * D + 2 * c);
    float h0 = (a00 + a10) * inv + sc.x; h0 = h0 > 0.0f ? h0 : 0.0f;
    float h1 = (a01 + a11) * inv + sc.y; h1 = h1 > 0.0f ? h1 : 0.0f;

    if (!LAYER2) {
        *(float2*)(h1o + (size_t)dst * D + 2 * c) = make_float2(h0, h1);
    } else {
        float p0 = h0 * woF[4 * c + 0] + h1 * woF[4 * c + 2];
        float p1 = h0 * woF[4 * c + 1] + h1 * woF[4 * c + 3];
#pragma unroll
        for (int m = LPD / 2; m >= 1; m >>= 1) {
            p0 += __shfl_xor(p0, m, LPD);
            p1 += __shfl_xor(p1, m, LPD);
        }
        if (c == 0) {
            float o0 = p0 + woF[32];
            float o1 = p1 + woF[33];
            if (flags[0]) {
                ((bf16*)out)[dst * 2 + 0] = __float2bfloat16(o0);
                ((bf16*)out)[dst * 2 + 1] = __float2bfloat16(o1);
            } else {
                ((float*)out)[dst * 2 + 0] = o0;
                ((float*)out)[dst * 2 + 1] = o1;
            }
        }
    }
}

extern "C" void kernel_launch(void* const* d_in, const int* in_sizes, int n_in,
                              void* d_out, int out_size, void* d_ws, size_t ws_size,
                              hipStream_t stream) {
    const int* ei  = (const int*)d_in[0];
    const void* emb = d_in[1];
    const void *Wq1 = d_in[2],  *bq1 = d_in[3];
    const void *Wk1 = d_in[4],  *bk1 = d_in[5];
    const void *Wv1 = d_in[6],  *bv1 = d_in[7];
    const void *Ws1 = d_in[8],  *bs1 = d_in[9];
    const void *Wq2 = d_in[10], *bq2 = d_in[11];
    const void *Wk2 = d_in[12], *bk2 = d_in[13];
    const void *Wv2 = d_in[14], *bv2 = d_in[15];
    const void *Ws2 = d_in[16], *bs2 = d_in[17];
    const void *Wo  = d_in[18], *bo  = d_in[19];

    // Workspace layout (floats). pairsSB aliases q (dead after radix_b).
    const size_t ND = (size_t)N_NODES * 32;
    const size_t SBTOT = (size_t)NSB * SBCAP;      // 2,007,040
    float* base   = (float*)d_ws;
    int*   flags  = (int*)base;                    // 64
    float* wp1    = base + 64;                     // 4096
    float* bp1    = wp1 + 4096;                    // 128
    float* wp2    = bp1 + 128;                     // 2048
    float* bp2    = wp2 + 2048;                    // 64
    float* woF    = bp2 + 64;                      // 64
    int*   curSB  = (int*)(woF + 64);              // 256
    int*   csums  = curSB + 256;                   // 256
    int*   coffs  = csums + 256;                   // 256
    int*   cnt    = coffs + 256;                   // PN (100,096)
    int*   cbase  = cnt + PN;                      // PN
    int*   rowbeg = cbase + PN;                    // N_NODES
    int*   rowend = rowbeg + N_NODES;              // N_NODES
    int*   perm   = rowend + N_NODES;              // N_NODES
    float* uni    = (float*)(perm + N_NODES);      // union start
    uint*  pairsSB = (uint*)uni;                   // SBTOT uints (8 MB, alias q)
    float* q      = uni;                           // ND
    float* s      = uni + ND;                      // ND
    ushort* kvb   = (ushort*)(uni + 2 * ND);       // 2*ND ushorts = ND floats
    float* h1     = uni + 3 * ND;                  // ND
    int*   esrc   = (int*)(uni + 4 * ND);          // SBTOT ints (8 MB)
    // total ~ 62 MB

    const int B = 256;
    const int gNL32   = (N_NODES + 31) / 32;           // 3125 (NPB=32)
    const int gNL16   = (N_NODES + 63) / 64;           // 1563 (NPB=64)
    const int gGat32  = ((N_NODES + 3) / 4 * 64 + B - 1) / B;   // 6250
    const int gGat16  = ((N_NODES + 7) / 8 * 64 + B - 1) / B;   // 3125
    const int gRadA   = (N_EDGES_C + RND - 1) / RND;   // 391
    const int gAdd2   = (PN + B - 1) / B;              // 392

    detect_kernel<<<1, 64, 0, stream>>>(emb, ei, flags);
    cast_params<<<1, B, 0, stream>>>(Wq1, bq1, Wk1, bk1, Wv1, bv1, Ws1, bs1,
                                     Wq2, bq2, Wk2, bk2, Wv2, bv2, Ws2, bs2,
                                     Wo, bo, flags, wp1, bp1, wp2, bp2, woF);

    // ---- CSR build via LDS-coalesced 2-level radix ----
    zero_i<<<1, B, 0, stream>>>(curSB, 256);
    radix_a<<<gRadA, B, 0, stream>>>(ei, flags, curSB, pairsSB);
    radix_b<<<NSB, B, 0, stream>>>(curSB, pairsSB, esrc, rowbeg, rowend);

    // ---- degree-sorted dst permutation (contention-free counting sort) ----
    deg_cnt<<<NBLKH, B, 0, stream>>>(rowbeg, rowend, cnt);
    scan_chunk2<<<PCH, 512, 0, stream>>>(cnt, cbase, csums);
    scan_sums2<<<1, 256, 0, stream>>>(csums, coffs);
    add_offs2<<<gAdd2, B, 0, stream>>>(cbase, coffs);
    perm_scatter2<<<NBLKH, B, 0, stream>>>(rowbeg, rowend, cbase, perm);

    // ---- Layer 1 (32 -> 32): dual gated variants, no separate cast ----
    node_linear<32, true ><<<gNL32, B, 0, stream>>>(emb, wp1, bp1, flags, 1, q, kvb, s);
    node_linear<32, false><<<gNL32, B, 0, stream>>>(emb, wp1, bp1, flags, 0, q, kvb, s);
    gather_attn<32, false><<<gGat32, B, 0, stream>>>(
        perm, rowbeg, rowend, esrc, q, kvb, s, woF, flags, h1, nullptr);

    // ---- Layer 2 (32 -> 16) + output linear ----
    node_linear<16, false><<<gNL16, B, 0, stream>>>(h1, wp2, bp2, flags, -1, q, kvb, s);
    gather_attn<16, true><<<gGat16, B, 0, stream>>>(
        perm, rowbeg, rowend, esrc, q, kvb, s, woF, flags, nullptr, d_out);
}

// Round 13
// 298.001 us; speedup vs baseline: 2.7731x; 1.0457x over previous
//
#include <hip/hip_runtime.h>
#include <hip/hip_bf16.h>

typedef __hip_bfloat16 bf16;
typedef unsigned int uint;
typedef unsigned short ushort;

#define N_NODES 100000
#define N_EDGES_C 1600000
#define NSB 196            // super-buckets: dst>>9 (512 dsts each); 196*512=100352
#define NSBP 200           // padded counter array size
#define SBCAP 10240        // per-SB region capacity (mean 8163, +23 sigma)
#define RND 4096           // edges per radix_a block
#define NBLKH 391          // perm-sort blocks: ceil(100000/256)
#define PN (256 * NBLKH)   // flattened (bin-major) count array: 100,096
#define PCH 196            // scan chunks of 512: ceil(PN/512)

// ---------- runtime dtype helpers (flags[0]=floats-are-bf16, flags[1]=indices-are-int64) ----------
__device__ __forceinline__ float ldf(const void* p, long i, int isbf) {
    return isbf ? __bfloat162float(((const bf16*)p)[i]) : ((const float*)p)[i];
}
__device__ __forceinline__ int ldidx(const int* ei, long pos, int is64) {
    return is64 ? ei[2 * pos] : ei[pos];   // int64 LE: low word at 2*pos
}
__device__ __forceinline__ ushort bfb(float x) {   // f32 -> bf16 bits (RNE)
    bf16 h = __float2bfloat16(x);
    return *(ushort*)&h;
}
__device__ __forceinline__ float bl(uint u) { return __uint_as_float(u << 16); }        // low bf16
__device__ __forceinline__ float bh(uint u) { return __uint_as_float(u & 0xFFFF0000u); } // high bf16

// ---------- dtype detection ----------
__global__ void detect_kernel(const void* emb, const int* ei, int* flags) {
    if (blockIdx.x == 0 && threadIdx.x == 0) {
        const bf16* pb = (const bf16*)emb;
        int big = 0;
        for (int i = 0; i < 256; i++) {
            float v = __bfloat162float(pb[i]);
            if (!(v > -1.0e6f && v < 1.0e6f)) big++;  // f32-viewed-as-bf16 => ~42% huge/nan
        }
        flags[0] = (big <= 8) ? 1 : 0;
        int nz = 0;
        for (int i = 1; i < 256; i += 2) nz += (ei[i] != 0) ? 1 : 0;
        flags[1] = (nz == 0) ? 1 : 0;     // int64 => odd int32 words all zero
    }
}

__global__ void cast_params(
    const void* Wq1, const void* bq1, const void* Wk1, const void* bk1,
    const void* Wv1, const void* bv1, const void* Ws1, const void* bs1,
    const void* Wq2, const void* bq2, const void* Wk2, const void* bk2,
    const void* Wv2, const void* bv2, const void* Ws2, const void* bs2,
    const void* Wo, const void* bo, const int* __restrict__ flags,
    float* __restrict__ wp1, float* __restrict__ bp1,
    float* __restrict__ wp2, float* __restrict__ bp2, float* __restrict__ woF) {
    int isbf = flags[0];
    int t = threadIdx.x;
    for (int i = t; i < 1024; i += 256) {
        wp1[i]        = ldf(Wq1, i, isbf);
        wp1[1024 + i] = ldf(Wk1, i, isbf);
        wp1[2048 + i] = ldf(Wv1, i, isbf);
        wp1[3072 + i] = ldf(Ws1, i, isbf);
    }
    for (int i = t; i < 512; i += 256) {
        wp2[i]        = ldf(Wq2, i, isbf);
        wp2[512 + i]  = ldf(Wk2, i, isbf);
        wp2[1024 + i] = ldf(Wv2, i, isbf);
        wp2[1536 + i] = ldf(Ws2, i, isbf);
    }
    if (t < 32) {
        bp1[t] = ldf(bq1, t, isbf); bp1[32 + t] = ldf(bk1, t, isbf);
        bp1[64 + t] = ldf(bv1, t, isbf); bp1[96 + t] = ldf(bs1, t, isbf);
        woF[t] = ldf(Wo, t, isbf);
    }
    if (t < 16) {
        bp2[t] = ldf(bq2, t, isbf); bp2[16 + t] = ldf(bk2, t, isbf);
        bp2[32 + t] = ldf(bv2, t, isbf); bp2[48 + t] = ldf(bs2, t, isbf);
    }
    if (t < 2) woF[32 + t] = ldf(bo, t, isbf);
}

__global__ void zero_i(int* __restrict__ p, int n) {
    int i = blockIdx.x * blockDim.x + threadIdx.x;
    if (i < n) p[i] = 0;
}

// ---------- Pass A: LDS-coalesced radix into 196 super-buckets ----------
__global__ void radix_a(const int* __restrict__ ei, const int* __restrict__ flags,
                        int* __restrict__ curSB, uint* __restrict__ pairsSB) {
    __shared__ int cnt[NSBP];
    __shared__ int excl[NSBP];
    __shared__ int gbase[NSBP];
    __shared__ uint sVal[RND];
    __shared__ unsigned char sSb[RND];
    const int is64 = flags[1];
    int t = threadIdx.x;
    for (int i = t; i < NSBP; i += 256) cnt[i] = 0;
    __syncthreads();
    long base = (long)blockIdx.x * RND;

    int mySb[16]; int myRank[16]; uint myPk[16];
#pragma unroll
    for (int r = 0; r < 16; r++) {
        long e = base + r * 256 + t;
        mySb[r] = -1;
        if (e < N_EDGES_C) {
            int d = ldidx(ei, (long)N_EDGES_C + e, is64);
            int s = ldidx(ei, e, is64);
            int sb = d >> 9;
            myPk[r] = (uint)s | ((uint)(d & 511) << 17);
            myRank[r] = atomicAdd(&cnt[sb], 1);
            mySb[r] = sb;
        }
    }
    __syncthreads();
    if (t == 0) {
        int o = 0;
        for (int i = 0; i < NSBP; i++) { excl[i] = o; o += cnt[i]; }
    }
    __syncthreads();
#pragma unroll
    for (int r = 0; r < 16; r++) {
        if (mySb[r] >= 0) {
            int pos = excl[mySb[r]] + myRank[r];
            sVal[pos] = myPk[r];
            sSb[pos] = (unsigned char)mySb[r];
        }
    }
    __syncthreads();
    for (int i = t; i < NSBP; i += 256)
        gbase[i] = (cnt[i] > 0) ? atomicAdd(&curSB[i], cnt[i]) : 0;
    __syncthreads();
    int tot = excl[NSBP - 1] + cnt[NSBP - 1];
    for (int i = t; i < tot; i += 256) {   // consecutive i in a run -> consecutive global addr
        int sb = sSb[i];
        int gp = gbase[sb] + (i - excl[sb]);
        if (gp < SBCAP)
            pairsSB[(size_t)sb * SBCAP + gp] = sVal[i];
    }
}

// ---------- Pass B: per-SB CSR build (512 dsts) ----------
__global__ void radix_b(const int* __restrict__ curSB, const uint* __restrict__ pairsSB,
                        int* __restrict__ esrc,
                        int* __restrict__ rowbeg, int* __restrict__ rowend) {
    __shared__ uint sP[SBCAP];                 // 40 KB
    __shared__ int dcnt[512], dexcl[512], dcur[512];
    int sb = blockIdx.x;
    int t = threadIdx.x;
    int n = min(curSB[sb], SBCAP);
    for (int i = t; i < 512; i += 256) { dcnt[i] = 0; dcur[i] = 0; }
    __syncthreads();
    for (int i = t; i < n; i += 256) {
        uint pk = pairsSB[(size_t)sb * SBCAP + i];
        sP[i] = pk;
        atomicAdd(&dcnt[(pk >> 17) & 511], 1);
    }
    __syncthreads();
    if (t == 0) {
        int o = 0;
        for (int j = 0; j < 512; j++) { dexcl[j] = o; o += dcnt[j]; }
    }
    __syncthreads();
    const int EB = sb * SBCAP;
    for (int j = t; j < 512; j += 256) {
        int dst = sb * 512 + j;
        if (dst < N_NODES) {
            rowbeg[dst] = EB + dexcl[j];
            rowend[dst] = EB + dexcl[j] + dcnt[j];
        }
    }
    for (int i = t; i < n; i += 256) {
        uint pk = sP[i];
        int j = (pk >> 17) & 511;
        int p = dexcl[j] + atomicAdd(&dcur[j], 1);
        esrc[EB + p] = (int)(pk & 0x1FFFF);
    }
}

// ---------- degree-sorted dst permutation (contention-free counting sort) ----------
__global__ void deg_cnt(const int* __restrict__ rowbeg, const int* __restrict__ rowend,
                        int* __restrict__ cnt) {
    __shared__ int h[256];
    int t = threadIdx.x, b = blockIdx.x;
    h[t] = 0;
    __syncthreads();
    int i = b * 256 + t;
    if (i < N_NODES) {
        int d = min(rowend[i] - rowbeg[i], 255);
        atomicAdd(&h[d], 1);            // LDS atomic
    }
    __syncthreads();
    cnt[t * NBLKH + b] = h[t];
}

__global__ void scan_chunk2(const int* __restrict__ x, int* __restrict__ y,
                            int* __restrict__ csums) {
    __shared__ int tmp[512];
    int i = blockIdx.x * 512 + threadIdx.x;
    int v = (i < PN) ? x[i] : 0;
    tmp[threadIdx.x] = v;
    __syncthreads();
    for (int off = 1; off < 512; off <<= 1) {
        int t = (threadIdx.x >= off) ? tmp[threadIdx.x - off] : 0;
        __syncthreads();
        tmp[threadIdx.x] += t;
        __syncthreads();
    }
    if (i < PN) y[i] = tmp[threadIdx.x] - v;  // exclusive
    if (threadIdx.x == 511) csums[blockIdx.x] = tmp[threadIdx.x];
}

__global__ void scan_sums2(int* __restrict__ csums, int* __restrict__ coffs) {
    __shared__ int tmp[256];
    int v = (threadIdx.x < PCH) ? csums[threadIdx.x] : 0;
    tmp[threadIdx.x] = v;
    __syncthreads();
    for (int off = 1; off < 256; off <<= 1) {
        int t = (threadIdx.x >= off) ? tmp[threadIdx.x - off] : 0;
        __syncthreads();
        tmp[threadIdx.x] += t;
        __syncthreads();
    }
    if (threadIdx.x < PCH) coffs[threadIdx.x] = tmp[threadIdx.x] - v;
}

__global__ void add_offs2(int* __restrict__ y, const int* __restrict__ coffs) {
    int i = blockIdx.x * blockDim.x + threadIdx.x;
    if (i < PN) y[i] += coffs[i / 512];
}

__global__ void perm_scatter2(const int* __restrict__ rowbeg, const int* __restrict__ rowend,
                              const int* __restrict__ basearr, int* __restrict__ perm) {
    __shared__ int cur[256];
    int t = threadIdx.x, b = blockIdx.x;
    cur[t] = 0;
    __syncthreads();
    int i = b * 256 + t;
    if (i < N_NODES) {
        int d = min(rowend[i] - rowbeg[i], 255);
        int r = atomicAdd(&cur[d], 1);  // LDS atomic
        perm[basearr[d * NBLKH + b] + r] = i;
    }
}

// ---------- node linears (gated dtype variants; kv packed bf16 out) ----------
template <int DOUT, bool XBF16>
__global__ void node_linear(const void* __restrict__ X,       // [N,32] bf16 or f32
                            const float* __restrict__ wpack,  // [4][32][DOUT] f32
                            const float* __restrict__ bpack,  // [4][DOUT] f32
                            const int* __restrict__ flags, int wantbf,
                            float* __restrict__ q, ushort* __restrict__ kvb,
                            float* __restrict__ s) {
    if (wantbf >= 0 && flags[0] != wantbf) return;
    const int TPN = DOUT / 4;     // threads per node (8 or 4)
    const int NPB = 256 / TPN;    // nodes per block (32 or 64)
    const int W_ELEMS = 4 * 32 * DOUT;
    __shared__ float sW[W_ELEMS];
    __shared__ float sb[4 * DOUT];
    __shared__ float sX[NPB * 36];  // pad stride 36 (16B-aligned, conflict-free)

    const float4* wp4 = (const float4*)wpack;
    float4* sW4 = (float4*)sW;
    for (int i = threadIdx.x; i < W_ELEMS / 4; i += 256) sW4[i] = wp4[i];
    if (threadIdx.x < 4 * DOUT) sb[threadIdx.x] = bpack[threadIdx.x];
    const int base = blockIdx.x * NPB * 32;
    for (int i = threadIdx.x; i < NPB * 32; i += 256) {
        int g = base + i;
        float xv = 0.0f;
        if (g < N_NODES * 32)
            xv = XBF16 ? __bfloat162float(((const bf16*)X)[g]) : ((const float*)X)[g];
        sX[(i >> 5) * 36 + (i & 31)] = xv;
    }
    __syncthreads();

    int l = threadIdx.x / TPN;
    int c4 = (threadIdx.x % TPN) * 4;
    int n = blockIdx.x * NPB + l;
    if (n >= N_NODES) return;

    float xr[32];
#pragma unroll
    for (int j = 0; j < 8; j++) {
        float4 t = *(const float4*)&sX[l * 36 + 4 * j];
        xr[4 * j] = t.x; xr[4 * j + 1] = t.y; xr[4 * j + 2] = t.z; xr[4 * j + 3] = t.w;
    }
    float acc[4][4];
#pragma unroll
    for (int m = 0; m < 4; m++)
#pragma unroll
        for (int j = 0; j < 4; j++) acc[m][j] = sb[m * DOUT + c4 + j];

#pragma unroll
    for (int t = 0; t < 32; t++) {
#pragma unroll
        for (int m = 0; m < 4; m++) {
            float4 w = *(const float4*)&sW[(m * 32 + t) * DOUT + c4];
            acc[m][0] += xr[t] * w.x;
            acc[m][1] += xr[t] * w.y;
            acc[m][2] += xr[t] * w.z;
            acc[m][3] += xr[t] * w.w;
        }
    }
    size_t o = (size_t)n * DOUT + c4;
    *(float4*)&q[o] = make_float4(acc[0][0], acc[0][1], acc[0][2], acc[0][3]);
    *(float4*)&s[o] = make_float4(acc[3][0], acc[3][1], acc[3][2], acc[3][3]);
    size_t okv = (size_t)n * 2 * DOUT + c4;
    ushort4 kp = make_ushort4(bfb(acc[1][0]), bfb(acc[1][1]), bfb(acc[1][2]), bfb(acc[1][3]));
    ushort4 vp = make_ushort4(bfb(acc[2][0]), bfb(acc[2][1]), bfb(acc[2][2]), bfb(acc[2][3]));
    *(ushort4*)&kvb[okv]        = kp;
    *(ushort4*)&kvb[okv + DOUT] = vp;
}

// ---------- fused gather attention: D/4 lanes per dst, uint2 (8B) kv loads ----------
// More dst groups per wave (8 for D=32, 16 for D=16) => 2x independent load
// streams in flight per wave (latency-bound kernel), shorter shfl reductions.
template <int D, bool LAYER2>
__global__ void gather_attn(const int* __restrict__ perm,
                            const int* __restrict__ rowbeg, const int* __restrict__ rowend,
                            const int* __restrict__ esrc,
                            const float* __restrict__ q, const ushort* __restrict__ kvb,
                            const float* __restrict__ s,
                            const float* __restrict__ woF,  // [32]=Wo, [32..33]=bo (f32)
                            const int* __restrict__ flags,
                            float* __restrict__ h1o, void* __restrict__ out) {
    const int LPD = D / 4;   // lanes per dst (8 or 4)
    const int G = 64 / LPD;  // dst groups per wave (8 or 16)
    int lane = threadIdx.x & 63;
    int wave = (blockIdx.x * blockDim.x + threadIdx.x) >> 6;
    int g = lane / LPD;
    int c = lane % LPD;      // dims 4c..4c+3
    int idx = wave * G + g;
    if (idx >= N_NODES) return;  // uniform within a group; shfl stays in-group
    int dst = perm[idx];         // degree-sorted: groups in wave have ~equal degree

    const float rsq = (D == 32) ? 0.17677669529663689f : 0.25f;  // 1/sqrt(D)
    float4 qc = *(const float4*)(q + (size_t)dst * D + 4 * c);
    int beg = rowbeg[dst], end = rowend[dst];

    const char* kvbase = (const char*)kvb;
    const int ROW = 4 * D;            // row bytes: [k bf16 x D | v bf16 x D]
    const int koff = 8 * c;
    const int voff = 2 * D + 8 * c;

    float sum0 = 0.f, sum1 = 0.f;
    float4 a0 = make_float4(0.f, 0.f, 0.f, 0.f);
    float4 a1 = make_float4(0.f, 0.f, 0.f, 0.f);

    // 2-deep software pipeline, unroll x2
    int sn0 = (beg < end) ? esrc[beg] : 0;
    int sn1 = (beg + 1 < end) ? esrc[beg + 1] : 0;
    const char* pa = kvbase + (size_t)sn0 * ROW;
    const char* pb = kvbase + (size_t)sn1 * ROW;
    uint2 kau = *(const uint2*)(pa + koff), vau = *(const uint2*)(pa + voff);
    uint2 kbu = *(const uint2*)(pb + koff), vbu = *(const uint2*)(pb + voff);

    for (int e = beg; e < end; e += 2) {
        uint2 kA = kau, vA = vau, kB = kbu, vB = vbu;
        if (e + 2 < end) {
            const char* p = kvbase + (size_t)esrc[e + 2] * ROW;
            kau = *(const uint2*)(p + koff); vau = *(const uint2*)(p + voff);
        }
        if (e + 3 < end) {
            const char* p = kvbase + (size_t)esrc[e + 3] * ROW;
            kbu = *(const uint2*)(p + koff); vbu = *(const uint2*)(p + voff);
        }
        float pd = qc.x * bl(kA.x) + qc.y * bh(kA.x) + qc.z * bl(kA.y) + qc.w * bh(kA.y);
#pragma unroll
        for (int m = LPD / 2; m >= 1; m >>= 1) pd += __shfl_xor(pd, m, LPD);
        float ex = __expf(fminf(fmaxf(pd * rsq, -80.0f), 80.0f));
        sum0 += ex;
        a0.x += bl(vA.x) * ex; a0.y += bh(vA.x) * ex;
        a0.z += bl(vA.y) * ex; a0.w += bh(vA.y) * ex;
        if (e + 1 < end) {
            float pd1 = qc.x * bl(kB.x) + qc.y * bh(kB.x) + qc.z * bl(kB.y) + qc.w * bh(kB.y);
#pragma unroll
            for (int m = LPD / 2; m >= 1; m >>= 1) pd1 += __shfl_xor(pd1, m, LPD);
            float ex1 = __expf(fminf(fmaxf(pd1 * rsq, -80.0f), 80.0f));
            sum1 += ex1;
            a1.x += bl(vB.x) * ex1; a1.y += bh(vB.x) * ex1;
            a1.z += bl(vB.y) * ex1; a1.w += bh(vB.y) * ex1;
        }
    }
    float inv = 1.0f / (sum0 + sum1 + 1e-16f);
    float4 sc = *(const float4*)(s + (size_t)dst * D + 4 * c);
    float4 h;
    h.x = (a0.x + a1.x) * inv + sc.x; h.x = h.x > 0.0f ? h.x : 0.0f;
    h.y = (a0.y + a1.y) * inv + sc.y; h.y = h.y > 0.0f ? h.y : 0.0f;
    h.z = (a0.z + a1.z) * inv + sc.z; h.z = h.z > 0.0f ? h.z : 0.0f;
    h.w = (a0.w + a1.w) * inv + sc.w; h.w = h.w > 0.0f ? h.w : 0.0f;

    if (!LAYER2) {
        *(float4*)(h1o + (size_t)dst * D + 4 * c) = h;
    } else {
        float p0 = h.x * woF[8 * c + 0] + h.y * woF[8 * c + 2]
                 + h.z * woF[8 * c + 4] + h.w * woF[8 * c + 6];
        float p1 = h.x * woF[8 * c + 1] + h.y * woF[8 * c + 3]
                 + h.z * woF[8 * c + 5] + h.w * woF[8 * c + 7];
#pragma unroll
        for (int m = LPD / 2; m >= 1; m >>= 1) {
            p0 += __shfl_xor(p0, m, LPD);
            p1 += __shfl_xor(p1, m, LPD);
        }
        if (c == 0) {
            float o0 = p0 + woF[32];
            float o1 = p1 + woF[33];
            if (flags[0]) {
                ((bf16*)out)[dst * 2 + 0] = __float2bfloat16(o0);
                ((bf16*)out)[dst * 2 + 1] = __float2bfloat16(o1);
            } else {
                ((float*)out)[dst * 2 + 0] = o0;
                ((float*)out)[dst * 2 + 1] = o1;
            }
        }
    }
}

extern "C" void kernel_launch(void* const* d_in, const int* in_sizes, int n_in,
                              void* d_out, int out_size, void* d_ws, size_t ws_size,
                              hipStream_t stream) {
    const int* ei  = (const int*)d_in[0];
    const void* emb = d_in[1];
    const void *Wq1 = d_in[2],  *bq1 = d_in[3];
    const void *Wk1 = d_in[4],  *bk1 = d_in[5];
    const void *Wv1 = d_in[6],  *bv1 = d_in[7];
    const void *Ws1 = d_in[8],  *bs1 = d_in[9];
    const void *Wq2 = d_in[10], *bq2 = d_in[11];
    const void *Wk2 = d_in[12], *bk2 = d_in[13];
    const void *Wv2 = d_in[14], *bv2 = d_in[15];
    const void *Ws2 = d_in[16], *bs2 = d_in[17];
    const void *Wo  = d_in[18], *bo  = d_in[19];

    // Workspace layout (floats). pairsSB aliases q (dead after radix_b).
    const size_t ND = (size_t)N_NODES * 32;
    const size_t SBTOT = (size_t)NSB * SBCAP;      // 2,007,040
    float* base   = (float*)d_ws;
    int*   flags  = (int*)base;                    // 64
    float* wp1    = base + 64;                     // 4096
    float* bp1    = wp1 + 4096;                    // 128
    float* wp2    = bp1 + 128;                     // 2048
    float* bp2    = wp2 + 2048;                    // 64
    float* woF    = bp2 + 64;                      // 64
    int*   curSB  = (int*)(woF + 64);              // 256
    int*   csums  = curSB + 256;                   // 256
    int*   coffs  = csums + 256;                   // 256
    int*   cnt    = coffs + 256;                   // PN (100,096)
    int*   cbase  = cnt + PN;                      // PN
    int*   rowbeg = cbase + PN;                    // N_NODES
    int*   rowend = rowbeg + N_NODES;              // N_NODES
    int*   perm   = rowend + N_NODES;              // N_NODES
    float* uni    = (float*)(perm + N_NODES);      // union start
    uint*  pairsSB = (uint*)uni;                   // SBTOT uints (8 MB, alias q)
    float* q      = uni;                           // ND
    float* s      = uni + ND;                      // ND
    ushort* kvb   = (ushort*)(uni + 2 * ND);       // 2*ND ushorts = ND floats
    float* h1     = uni + 3 * ND;                  // ND
    int*   esrc   = (int*)(uni + 4 * ND);          // SBTOT ints (8 MB)
    // total ~ 62 MB

    const int B = 256;
    const int gNL32   = (N_NODES + 31) / 32;           // 3125 (NPB=32)
    const int gNL16   = (N_NODES + 63) / 64;           // 1563 (NPB=64)
    const int gGat32  = ((N_NODES + 7) / 8 * 64 + B - 1) / B;    // G=8 -> 3125
    const int gGat16  = ((N_NODES + 15) / 16 * 64 + B - 1) / B;  // G=16 -> 1563
    const int gRadA   = (N_EDGES_C + RND - 1) / RND;   // 391
    const int gAdd2   = (PN + B - 1) / B;              // 392

    detect_kernel<<<1, 64, 0, stream>>>(emb, ei, flags);
    cast_params<<<1, B, 0, stream>>>(Wq1, bq1, Wk1, bk1, Wv1, bv1, Ws1, bs1,
                                     Wq2, bq2, Wk2, bk2, Wv2, bv2, Ws2, bs2,
                                     Wo, bo, flags, wp1, bp1, wp2, bp2, woF);

    // ---- CSR build via LDS-coalesced 2-level radix ----
    zero_i<<<1, B, 0, stream>>>(curSB, 256);
    radix_a<<<gRadA, B, 0, stream>>>(ei, flags, curSB, pairsSB);
    radix_b<<<NSB, B, 0, stream>>>(curSB, pairsSB, esrc, rowbeg, rowend);

    // ---- degree-sorted dst permutation (contention-free counting sort) ----
    deg_cnt<<<NBLKH, B, 0, stream>>>(rowbeg, rowend, cnt);
    scan_chunk2<<<PCH, 512, 0, stream>>>(cnt, cbase, csums);
    scan_sums2<<<1, 256, 0, stream>>>(csums, coffs);
    add_offs2<<<gAdd2, B, 0, stream>>>(cbase, coffs);
    perm_scatter2<<<NBLKH, B, 0, stream>>>(rowbeg, rowend, cbase, perm);

    // ---- Layer 1 (32 -> 32): dual gated variants, no separate cast ----
    node_linear<32, true ><<<gNL32, B, 0, stream>>>(emb, wp1, bp1, flags, 1, q, kvb, s);
    node_linear<32, false><<<gNL32, B, 0, stream>>>(emb, wp1, bp1, flags, 0, q, kvb, s);
    gather_attn<32, false><<<gGat32, B, 0, stream>>>(
        perm, rowbeg, rowend, esrc, q, kvb, s, woF, flags, h1, nullptr);

    // ---- Layer 2 (32 -> 16) + output linear ----
    node_linear<16, false><<<gNL16, B, 0, stream>>>(h1, wp2, bp2, flags, -1, q, kvb, s);
    gather_attn<16, true><<<gGat16, B, 0, stream>>>(
        perm, rowbeg, rowend, esrc, q, kvb, s, woF, flags, nullptr, d_out);
}

// Round 14
// 297.277 us; speedup vs baseline: 2.7799x; 1.0024x over previous
//
#include <hip/hip_runtime.h>
#include <hip/hip_bf16.h>

typedef __hip_bfloat16 bf16;
typedef unsigned int uint;
typedef unsigned short ushort;

#define N_NODES 100000
#define N_EDGES_C 1600000
#define NSB 196            // super-buckets: dst>>9 (512 dsts each); 196*512=100352
#define NSBP 200           // padded counter array size
#define SBCAP 10240        // per-SB region capacity (mean 8163, +23 sigma)
#define RND 4096           // edges per radix_a block
#define NBLKH 391          // perm-sort blocks: ceil(100000/256)
#define PN (256 * NBLKH)   // flattened (bin-major) count array: 100,096
#define PCH 196            // scan chunks of 512: ceil(PN/512)

// ---------- runtime dtype helpers (flags[0]=floats-are-bf16, flags[1]=indices-are-int64) ----------
__device__ __forceinline__ float ldf(const void* p, long i, int isbf) {
    return isbf ? __bfloat162float(((const bf16*)p)[i]) : ((const float*)p)[i];
}
__device__ __forceinline__ int ldidx(const int* ei, long pos, int is64) {
    return is64 ? ei[2 * pos] : ei[pos];   // int64 LE: low word at 2*pos
}
__device__ __forceinline__ ushort bfb(float x) {   // f32 -> bf16 bits (RNE)
    bf16 h = __float2bfloat16(x);
    return *(ushort*)&h;
}
__device__ __forceinline__ float bl(uint u) { return __uint_as_float(u << 16); }        // low bf16
__device__ __forceinline__ float bh(uint u) { return __uint_as_float(u & 0xFFFF0000u); } // high bf16

// ---------- dtype detection ----------
__global__ void detect_kernel(const void* emb, const int* ei, int* flags) {
    if (blockIdx.x == 0 && threadIdx.x == 0) {
        const bf16* pb = (const bf16*)emb;
        int big = 0;
        for (int i = 0; i < 256; i++) {
            float v = __bfloat162float(pb[i]);
            if (!(v > -1.0e6f && v < 1.0e6f)) big++;  // f32-viewed-as-bf16 => ~42% huge/nan
        }
        flags[0] = (big <= 8) ? 1 : 0;
        int nz = 0;
        for (int i = 1; i < 256; i += 2) nz += (ei[i] != 0) ? 1 : 0;
        flags[1] = (nz == 0) ? 1 : 0;     // int64 => odd int32 words all zero
    }
}

__global__ void cast_params(
    const void* Wq1, const void* bq1, const void* Wk1, const void* bk1,
    const void* Wv1, const void* bv1, const void* Ws1, const void* bs1,
    const void* Wq2, const void* bq2, const void* Wk2, const void* bk2,
    const void* Wv2, const void* bv2, const void* Ws2, const void* bs2,
    const void* Wo, const void* bo, const int* __restrict__ flags,
    float* __restrict__ wp1, float* __restrict__ bp1,
    float* __restrict__ wp2, float* __restrict__ bp2, float* __restrict__ woF) {
    int isbf = flags[0];
    int t = threadIdx.x;
    for (int i = t; i < 1024; i += 256) {
        wp1[i]        = ldf(Wq1, i, isbf);
        wp1[1024 + i] = ldf(Wk1, i, isbf);
        wp1[2048 + i] = ldf(Wv1, i, isbf);
        wp1[3072 + i] = ldf(Ws1, i, isbf);
    }
    for (int i = t; i < 512; i += 256) {
        wp2[i]        = ldf(Wq2, i, isbf);
        wp2[512 + i]  = ldf(Wk2, i, isbf);
        wp2[1024 + i] = ldf(Wv2, i, isbf);
        wp2[1536 + i] = ldf(Ws2, i, isbf);
    }
    if (t < 32) {
        bp1[t] = ldf(bq1, t, isbf); bp1[32 + t] = ldf(bk1, t, isbf);
        bp1[64 + t] = ldf(bv1, t, isbf); bp1[96 + t] = ldf(bs1, t, isbf);
        woF[t] = ldf(Wo, t, isbf);
    }
    if (t < 16) {
        bp2[t] = ldf(bq2, t, isbf); bp2[16 + t] = ldf(bk2, t, isbf);
        bp2[32 + t] = ldf(bv2, t, isbf); bp2[48 + t] = ldf(bs2, t, isbf);
    }
    if (t < 2) woF[32 + t] = ldf(bo, t, isbf);
}

__global__ void zero_i(int* __restrict__ p, int n) {
    int i = blockIdx.x * blockDim.x + threadIdx.x;
    if (i < n) p[i] = 0;
}

// ---------- Pass A: LDS-coalesced radix into 196 super-buckets ----------
__global__ void radix_a(const int* __restrict__ ei, const int* __restrict__ flags,
                        int* __restrict__ curSB, uint* __restrict__ pairsSB) {
    __shared__ int cnt[NSBP];
    __shared__ int excl[NSBP];
    __shared__ int gbase[NSBP];
    __shared__ uint sVal[RND];
    __shared__ unsigned char sSb[RND];
    const int is64 = flags[1];
    int t = threadIdx.x;
    for (int i = t; i < NSBP; i += 256) cnt[i] = 0;
    __syncthreads();
    long base = (long)blockIdx.x * RND;

    int mySb[16]; int myRank[16]; uint myPk[16];
#pragma unroll
    for (int r = 0; r < 16; r++) {
        long e = base + r * 256 + t;
        mySb[r] = -1;
        if (e < N_EDGES_C) {
            int d = ldidx(ei, (long)N_EDGES_C + e, is64);
            int s = ldidx(ei, e, is64);
            int sb = d >> 9;
            myPk[r] = (uint)s | ((uint)(d & 511) << 17);
            myRank[r] = atomicAdd(&cnt[sb], 1);
            mySb[r] = sb;
        }
    }
    __syncthreads();
    if (t == 0) {
        int o = 0;
        for (int i = 0; i < NSBP; i++) { excl[i] = o; o += cnt[i]; }
    }
    __syncthreads();
#pragma unroll
    for (int r = 0; r < 16; r++) {
        if (mySb[r] >= 0) {
            int pos = excl[mySb[r]] + myRank[r];
            sVal[pos] = myPk[r];
            sSb[pos] = (unsigned char)mySb[r];
        }
    }
    __syncthreads();
    for (int i = t; i < NSBP; i += 256)
        gbase[i] = (cnt[i] > 0) ? atomicAdd(&curSB[i], cnt[i]) : 0;
    __syncthreads();
    int tot = excl[NSBP - 1] + cnt[NSBP - 1];
    for (int i = t; i < tot; i += 256) {   // consecutive i in a run -> consecutive global addr
        int sb = sSb[i];
        int gp = gbase[sb] + (i - excl[sb]);
        if (gp < SBCAP)
            pairsSB[(size_t)sb * SBCAP + gp] = sVal[i];
    }
}

// ---------- Pass B: per-SB CSR build (512 dsts) ----------
__global__ void radix_b(const int* __restrict__ curSB, const uint* __restrict__ pairsSB,
                        int* __restrict__ esrc,
                        int* __restrict__ rowbeg, int* __restrict__ rowend) {
    __shared__ uint sP[SBCAP];                 // 40 KB
    __shared__ int dcnt[512], dexcl[512], dcur[512];
    int sb = blockIdx.x;
    int t = threadIdx.x;
    int n = min(curSB[sb], SBCAP);
    for (int i = t; i < 512; i += 256) { dcnt[i] = 0; dcur[i] = 0; }
    __syncthreads();
    for (int i = t; i < n; i += 256) {
        uint pk = pairsSB[(size_t)sb * SBCAP + i];
        sP[i] = pk;
        atomicAdd(&dcnt[(pk >> 17) & 511], 1);
    }
    __syncthreads();
    if (t == 0) {
        int o = 0;
        for (int j = 0; j < 512; j++) { dexcl[j] = o; o += dcnt[j]; }
    }
    __syncthreads();
    const int EB = sb * SBCAP;
    for (int j = t; j < 512; j += 256) {
        int dst = sb * 512 + j;
        if (dst < N_NODES) {
            rowbeg[dst] = EB + dexcl[j];
            rowend[dst] = EB + dexcl[j] + dcnt[j];
        }
    }
    for (int i = t; i < n; i += 256) {
        uint pk = sP[i];
        int j = (pk >> 17) & 511;
        int p = dexcl[j] + atomicAdd(&dcur[j], 1);
        esrc[EB + p] = (int)(pk & 0x1FFFF);
    }
}

// ---------- degree-sorted dst permutation (contention-free counting sort) ----------
__global__ void deg_cnt(const int* __restrict__ rowbeg, const int* __restrict__ rowend,
                        int* __restrict__ cnt) {
    __shared__ int h[256];
    int t = threadIdx.x, b = blockIdx.x;
    h[t] = 0;
    __syncthreads();
    int i = b * 256 + t;
    if (i < N_NODES) {
        int d = min(rowend[i] - rowbeg[i], 255);
        atomicAdd(&h[d], 1);            // LDS atomic
    }
    __syncthreads();
    cnt[t * NBLKH + b] = h[t];
}

__global__ void scan_chunk2(const int* __restrict__ x, int* __restrict__ y,
                            int* __restrict__ csums) {
    __shared__ int tmp[512];
    int i = blockIdx.x * 512 + threadIdx.x;
    int v = (i < PN) ? x[i] : 0;
    tmp[threadIdx.x] = v;
    __syncthreads();
    for (int off = 1; off < 512; off <<= 1) {
        int t = (threadIdx.x >= off) ? tmp[threadIdx.x - off] : 0;
        __syncthreads();
        tmp[threadIdx.x] += t;
        __syncthreads();
    }
    if (i < PN) y[i] = tmp[threadIdx.x] - v;  // exclusive
    if (threadIdx.x == 511) csums[blockIdx.x] = tmp[threadIdx.x];
}

__global__ void scan_sums2(int* __restrict__ csums, int* __restrict__ coffs) {
    __shared__ int tmp[256];
    int v = (threadIdx.x < PCH) ? csums[threadIdx.x] : 0;
    tmp[threadIdx.x] = v;
    __syncthreads();
    for (int off = 1; off < 256; off <<= 1) {
        int t = (threadIdx.x >= off) ? tmp[threadIdx.x - off] : 0;
        __syncthreads();
        tmp[threadIdx.x] += t;
        __syncthreads();
    }
    if (threadIdx.x < PCH) coffs[threadIdx.x] = tmp[threadIdx.x] - v;
}

__global__ void add_offs2(int* __restrict__ y, const int* __restrict__ coffs) {
    int i = blockIdx.x * blockDim.x + threadIdx.x;
    if (i < PN) y[i] += coffs[i / 512];
}

__global__ void perm_scatter2(const int* __restrict__ rowbeg, const int* __restrict__ rowend,
                              const int* __restrict__ basearr, int* __restrict__ perm) {
    __shared__ int cur[256];
    int t = threadIdx.x, b = blockIdx.x;
    cur[t] = 0;
    __syncthreads();
    int i = b * 256 + t;
    if (i < N_NODES) {
        int d = min(rowend[i] - rowbeg[i], 255);
        int r = atomicAdd(&cur[d], 1);  // LDS atomic
        perm[basearr[d * NBLKH + b] + r] = i;
    }
}

// ---------- node linears (gated dtype variants; kv packed bf16 out) ----------
template <int DOUT, bool XBF16>
__global__ void node_linear(const void* __restrict__ X,       // [N,32] bf16 or f32
                            const float* __restrict__ wpack,  // [4][32][DOUT] f32
                            const float* __restrict__ bpack,  // [4][DOUT] f32
                            const int* __restrict__ flags, int wantbf,
                            float* __restrict__ q, ushort* __restrict__ kvb,
                            float* __restrict__ s) {
    if (wantbf >= 0 && flags[0] != wantbf) return;
    const int TPN = DOUT / 4;     // threads per node (8 or 4)
    const int NPB = 256 / TPN;    // nodes per block (32 or 64)
    const int W_ELEMS = 4 * 32 * DOUT;
    __shared__ float sW[W_ELEMS];
    __shared__ float sb[4 * DOUT];
    __shared__ float sX[NPB * 36];  // pad stride 36 (16B-aligned, conflict-free)

    const float4* wp4 = (const float4*)wpack;
    float4* sW4 = (float4*)sW;
    for (int i = threadIdx.x; i < W_ELEMS / 4; i += 256) sW4[i] = wp4[i];
    if (threadIdx.x < 4 * DOUT) sb[threadIdx.x] = bpack[threadIdx.x];
    const int base = blockIdx.x * NPB * 32;
    for (int i = threadIdx.x; i < NPB * 32; i += 256) {
        int g = base + i;
        float xv = 0.0f;
        if (g < N_NODES * 32)
            xv = XBF16 ? __bfloat162float(((const bf16*)X)[g]) : ((const float*)X)[g];
        sX[(i >> 5) * 36 + (i & 31)] = xv;
    }
    __syncthreads();

    int l = threadIdx.x / TPN;
    int c4 = (threadIdx.x % TPN) * 4;
    int n = blockIdx.x * NPB + l;
    if (n >= N_NODES) return;

    float xr[32];
#pragma unroll
    for (int j = 0; j < 8; j++) {
        float4 t = *(const float4*)&sX[l * 36 + 4 * j];
        xr[4 * j] = t.x; xr[4 * j + 1] = t.y; xr[4 * j + 2] = t.z; xr[4 * j + 3] = t.w;
    }
    float acc[4][4];
#pragma unroll
    for (int m = 0; m < 4; m++)
#pragma unroll
        for (int j = 0; j < 4; j++) acc[m][j] = sb[m * DOUT + c4 + j];

#pragma unroll
    for (int t = 0; t < 32; t++) {
#pragma unroll
        for (int m = 0; m < 4; m++) {
            float4 w = *(const float4*)&sW[(m * 32 + t) * DOUT + c4];
            acc[m][0] += xr[t] * w.x;
            acc[m][1] += xr[t] * w.y;
            acc[m][2] += xr[t] * w.z;
            acc[m][3] += xr[t] * w.w;
        }
    }
    size_t o = (size_t)n * DOUT + c4;
    *(float4*)&q[o] = make_float4(acc[0][0], acc[0][1], acc[0][2], acc[0][3]);
    *(float4*)&s[o] = make_float4(acc[3][0], acc[3][1], acc[3][2], acc[3][3]);
    size_t okv = (size_t)n * 2 * DOUT + c4;
    ushort4 kp = make_ushort4(bfb(acc[1][0]), bfb(acc[1][1]), bfb(acc[1][2]), bfb(acc[1][3]));
    ushort4 vp = make_ushort4(bfb(acc[2][0]), bfb(acc[2][1]), bfb(acc[2][2]), bfb(acc[2][3]));
    *(ushort4*)&kvb[okv]        = kp;
    *(ushort4*)&kvb[okv + DOUT] = vp;
}

// ---------- fused gather attention: D/8 lanes per dst, uint4 (16B) kv loads ----------
// G=16 (D=32) / G=32 (D=16) dst groups per wave => 32 independent load streams
// in flight per wave (latency-bound kernel), 2-step (1-step) shfl reductions.
template <int D, bool LAYER2>
__global__ void gather_attn(const int* __restrict__ perm,
                            const int* __restrict__ rowbeg, const int* __restrict__ rowend,
                            const int* __restrict__ esrc,
                            const float* __restrict__ q, const ushort* __restrict__ kvb,
                            const float* __restrict__ s,
                            const float* __restrict__ woF,  // [32]=Wo, [32..33]=bo (f32)
                            const int* __restrict__ flags,
                            float* __restrict__ h1o, void* __restrict__ out) {
    const int LPD = D / 8;   // lanes per dst (4 or 2)
    const int G = 64 / LPD;  // dst groups per wave (16 or 32)
    int lane = threadIdx.x & 63;
    int wave = (blockIdx.x * blockDim.x + threadIdx.x) >> 6;
    int g = lane / LPD;
    int c = lane % LPD;      // dims 8c..8c+7
    int idx = wave * G + g;
    if (idx >= N_NODES) return;  // uniform within a group; shfl stays in-group
    int dst = perm[idx];         // degree-sorted: groups in wave have ~equal degree

    const float rsq = (D == 32) ? 0.17677669529663689f : 0.25f;  // 1/sqrt(D)
    float4 qa = *(const float4*)(q + (size_t)dst * D + 8 * c);
    float4 qb = *(const float4*)(q + (size_t)dst * D + 8 * c + 4);
    int beg = rowbeg[dst], end = rowend[dst];

    const char* kvbase = (const char*)kvb;
    const int ROW = 4 * D;            // row bytes: [k bf16 x D | v bf16 x D]
    const int koff = 16 * c;          // 8 dims x 2B
    const int voff = 2 * D + 16 * c;

    float sum0 = 0.f, sum1 = 0.f;
    float a0[8] = {0,0,0,0,0,0,0,0};
    float a1[8] = {0,0,0,0,0,0,0,0};

    // 2-deep software pipeline, unroll x2
    int sn0 = (beg < end) ? esrc[beg] : 0;
    int sn1 = (beg + 1 < end) ? esrc[beg + 1] : 0;
    const char* pa = kvbase + (size_t)sn0 * ROW;
    const char* pb = kvbase + (size_t)sn1 * ROW;
    uint4 kau = *(const uint4*)(pa + koff), vau = *(const uint4*)(pa + voff);
    uint4 kbu = *(const uint4*)(pb + koff), vbu = *(const uint4*)(pb + voff);

    for (int e = beg; e < end; e += 2) {
        uint4 kA = kau, vA = vau, kB = kbu, vB = vbu;
        if (e + 2 < end) {
            const char* p = kvbase + (size_t)esrc[e + 2] * ROW;
            kau = *(const uint4*)(p + koff); vau = *(const uint4*)(p + voff);
        }
        if (e + 3 < end) {
            const char* p = kvbase + (size_t)esrc[e + 3] * ROW;
            kbu = *(const uint4*)(p + koff); vbu = *(const uint4*)(p + voff);
        }
        float pd = qa.x * bl(kA.x) + qa.y * bh(kA.x) + qa.z * bl(kA.y) + qa.w * bh(kA.y)
                 + qb.x * bl(kA.z) + qb.y * bh(kA.z) + qb.z * bl(kA.w) + qb.w * bh(kA.w);
#pragma unroll
        for (int m = LPD / 2; m >= 1; m >>= 1) pd += __shfl_xor(pd, m, LPD);
        float ex = __expf(fminf(fmaxf(pd * rsq, -80.0f), 80.0f));
        sum0 += ex;
        a0[0] += bl(vA.x) * ex; a0[1] += bh(vA.x) * ex;
        a0[2] += bl(vA.y) * ex; a0[3] += bh(vA.y) * ex;
        a0[4] += bl(vA.z) * ex; a0[5] += bh(vA.z) * ex;
        a0[6] += bl(vA.w) * ex; a0[7] += bh(vA.w) * ex;
        if (e + 1 < end) {
            float pd1 = qa.x * bl(kB.x) + qa.y * bh(kB.x) + qa.z * bl(kB.y) + qa.w * bh(kB.y)
                      + qb.x * bl(kB.z) + qb.y * bh(kB.z) + qb.z * bl(kB.w) + qb.w * bh(kB.w);
#pragma unroll
            for (int m = LPD / 2; m >= 1; m >>= 1) pd1 += __shfl_xor(pd1, m, LPD);
            float ex1 = __expf(fminf(fmaxf(pd1 * rsq, -80.0f), 80.0f));
            sum1 += ex1;
            a1[0] += bl(vB.x) * ex1; a1[1] += bh(vB.x) * ex1;
            a1[2] += bl(vB.y) * ex1; a1[3] += bh(vB.y) * ex1;
            a1[4] += bl(vB.z) * ex1; a1[5] += bh(vB.z) * ex1;
            a1[6] += bl(vB.w) * ex1; a1[7] += bh(vB.w) * ex1;
        }
    }
    float inv = 1.0f / (sum0 + sum1 + 1e-16f);
    float4 sa = *(const float4*)(s + (size_t)dst * D + 8 * c);
    float4 sb2 = *(const float4*)(s + (size_t)dst * D + 8 * c + 4);
    float h[8];
    h[0] = (a0[0] + a1[0]) * inv + sa.x;  h[1] = (a0[1] + a1[1]) * inv + sa.y;
    h[2] = (a0[2] + a1[2]) * inv + sa.z;  h[3] = (a0[3] + a1[3]) * inv + sa.w;
    h[4] = (a0[4] + a1[4]) * inv + sb2.x; h[5] = (a0[5] + a1[5]) * inv + sb2.y;
    h[6] = (a0[6] + a1[6]) * inv + sb2.z; h[7] = (a0[7] + a1[7]) * inv + sb2.w;
#pragma unroll
    for (int j = 0; j < 8; j++) h[j] = h[j] > 0.0f ? h[j] : 0.0f;

    if (!LAYER2) {
        *(float4*)(h1o + (size_t)dst * D + 8 * c)     = make_float4(h[0], h[1], h[2], h[3]);
        *(float4*)(h1o + (size_t)dst * D + 8 * c + 4) = make_float4(h[4], h[5], h[6], h[7]);
    } else {
        float p0 = 0.f, p1 = 0.f;
#pragma unroll
        for (int j = 0; j < 8; j++) {
            p0 += h[j] * woF[(8 * c + j) * 2 + 0];
            p1 += h[j] * woF[(8 * c + j) * 2 + 1];
        }
#pragma unroll
        for (int m = LPD / 2; m >= 1; m >>= 1) {
            p0 += __shfl_xor(p0, m, LPD);
            p1 += __shfl_xor(p1, m, LPD);
        }
        if (c == 0) {
            float o0 = p0 + woF[32];
            float o1 = p1 + woF[33];
            if (flags[0]) {
                ((bf16*)out)[dst * 2 + 0] = __float2bfloat16(o0);
                ((bf16*)out)[dst * 2 + 1] = __float2bfloat16(o1);
            } else {
                ((float*)out)[dst * 2 + 0] = o0;
                ((float*)out)[dst * 2 + 1] = o1;
            }
        }
    }
}

extern "C" void kernel_launch(void* const* d_in, const int* in_sizes, int n_in,
                              void* d_out, int out_size, void* d_ws, size_t ws_size,
                              hipStream_t stream) {
    const int* ei  = (const int*)d_in[0];
    const void* emb = d_in[1];
    const void *Wq1 = d_in[2],  *bq1 = d_in[3];
    const void *Wk1 = d_in[4],  *bk1 = d_in[5];
    const void *Wv1 = d_in[6],  *bv1 = d_in[7];
    const void *Ws1 = d_in[8],  *bs1 = d_in[9];
    const void *Wq2 = d_in[10], *bq2 = d_in[11];
    const void *Wk2 = d_in[12], *bk2 = d_in[13];
    const void *Wv2 = d_in[14], *bv2 = d_in[15];
    const void *Ws2 = d_in[16], *bs2 = d_in[17];
    const void *Wo  = d_in[18], *bo  = d_in[19];

    // Workspace layout (floats). pairsSB aliases q (dead after radix_b).
    const size_t ND = (size_t)N_NODES * 32;
    const size_t SBTOT = (size_t)NSB * SBCAP;      // 2,007,040
    float* base   = (float*)d_ws;
    int*   flags  = (int*)base;                    // 64
    float* wp1    = base + 64;                     // 4096
    float* bp1    = wp1 + 4096;                    // 128
    float* wp2    = bp1 + 128;                     // 2048
    float* bp2    = wp2 + 2048;                    // 64
    float* woF    = bp2 + 64;                      // 64
    int*   curSB  = (int*)(woF + 64);              // 256
    int*   csums  = curSB + 256;                   // 256
    int*   coffs  = csums + 256;                   // 256
    int*   cnt    = coffs + 256;                   // PN (100,096)
    int*   cbase  = cnt + PN;                      // PN
    int*   rowbeg = cbase + PN;                    // N_NODES
    int*   rowend = rowbeg + N_NODES;              // N_NODES
    int*   perm   = rowend + N_NODES;              // N_NODES
    float* uni    = (float*)(perm + N_NODES);      // union start
    uint*  pairsSB = (uint*)uni;                   // SBTOT uints (8 MB, alias q)
    float* q      = uni;                           // ND
    float* s      = uni + ND;                      // ND
    ushort* kvb   = (ushort*)(uni + 2 * ND);       // 2*ND ushorts = ND floats
    float* h1     = uni + 3 * ND;                  // ND
    int*   esrc   = (int*)(uni + 4 * ND);          // SBTOT ints (8 MB)
    // total ~ 62 MB

    const int B = 256;
    const int gNL32   = (N_NODES + 31) / 32;           // 3125 (NPB=32)
    const int gNL16   = (N_NODES + 63) / 64;           // 1563 (NPB=64)
    const int gGat32  = ((N_NODES + 15) / 16 * 64 + B - 1) / B;  // G=16 -> 1563
    const int gGat16  = ((N_NODES + 31) / 32 * 64 + B - 1) / B;  // G=32 -> 782
    const int gRadA   = (N_EDGES_C + RND - 1) / RND;   // 391
    const int gAdd2   = (PN + B - 1) / B;              // 392

    detect_kernel<<<1, 64, 0, stream>>>(emb, ei, flags);
    cast_params<<<1, B, 0, stream>>>(Wq1, bq1, Wk1, bk1, Wv1, bv1, Ws1, bs1,
                                     Wq2, bq2, Wk2, bk2, Wv2, bv2, Ws2, bs2,
                                     Wo, bo, flags, wp1, bp1, wp2, bp2, woF);

    // ---- CSR build via LDS-coalesced 2-level radix ----
    zero_i<<<1, B, 0, stream>>>(curSB, 256);
    radix_a<<<gRadA, B, 0, stream>>>(ei, flags, curSB, pairsSB);
    radix_b<<<NSB, B, 0, stream>>>(curSB, pairsSB, esrc, rowbeg, rowend);

    // ---- degree-sorted dst permutation (contention-free counting sort) ----
    deg_cnt<<<NBLKH, B, 0, stream>>>(rowbeg, rowend, cnt);
    scan_chunk2<<<PCH, 512, 0, stream>>>(cnt, cbase, csums);
    scan_sums2<<<1, 256, 0, stream>>>(csums, coffs);
    add_offs2<<<gAdd2, B, 0, stream>>>(cbase, coffs);
    perm_scatter2<<<NBLKH, B, 0, stream>>>(rowbeg, rowend, cbase, perm);

    // ---- Layer 1 (32 -> 32): dual gated variants, no separate cast ----
    node_linear<32, true ><<<gNL32, B, 0, stream>>>(emb, wp1, bp1, flags, 1, q, kvb, s);
    node_linear<32, false><<<gNL32, B, 0, stream>>>(emb, wp1, bp1, flags, 0, q, kvb, s);
    gather_attn<32, false><<<gGat32, B, 0, stream>>>(
        perm, rowbeg, rowend, esrc, q, kvb, s, woF, flags, h1, nullptr);

    // ---- Layer 2 (32 -> 16) + output linear ----
    node_linear<16, false><<<gNL16, B, 0, stream>>>(h1, wp2, bp2, flags, -1, q, kvb, s);
    gather_attn<16, true><<<gGat16, B, 0, stream>>>(
        perm, rowbeg, rowend, esrc, q, kvb, s, woF, flags, nullptr, d_out);
}

// Round 15
// 295.801 us; speedup vs baseline: 2.7938x; 1.0050x over previous
//
#include <hip/hip_runtime.h>
#include <hip/hip_bf16.h>

typedef __hip_bfloat16 bf16;
typedef unsigned int uint;
typedef unsigned short ushort;

#define N_NODES 100000
#define N_EDGES_C 1600000
#define NSB 196            // super-buckets: dst>>9 (512 dsts each); 196*512=100352
#define NSBP 200           // padded counter array size
#define SBCAP 10240        // per-SB region capacity (mean 8163, +23 sigma)
#define RND 4096           // edges per radix_a block
#define NBIN 64            // degree bins (Poisson(16): max deg ~50; cap only affects balance)
#define CNT_N (NBIN * NSB) // 12544

// ---------- runtime dtype helpers (flags[0]=floats-are-bf16, flags[1]=indices-are-int64) ----------
__device__ __forceinline__ float ldf(const void* p, long i, int isbf) {
    return isbf ? __bfloat162float(((const bf16*)p)[i]) : ((const float*)p)[i];
}
__device__ __forceinline__ int ldidx(const int* ei, long pos, int is64) {
    return is64 ? ei[2 * pos] : ei[pos];   // int64 LE: low word at 2*pos
}
__device__ __forceinline__ ushort bfb(float x) {   // f32 -> bf16 bits (RNE)
    bf16 h = __float2bfloat16(x);
    return *(ushort*)&h;
}
__device__ __forceinline__ float bl(uint u) { return __uint_as_float(u << 16); }        // low bf16
__device__ __forceinline__ float bh(uint u) { return __uint_as_float(u & 0xFFFF0000u); } // high bf16

// ---------- setup: detect dtypes + cast params + zero curSB (one launch) ----------
__global__ void setup_kernel(
    const void* emb, const int* ei,
    const void* Wq1, const void* bq1, const void* Wk1, const void* bk1,
    const void* Wv1, const void* bv1, const void* Ws1, const void* bs1,
    const void* Wq2, const void* bq2, const void* Wk2, const void* bk2,
    const void* Wv2, const void* bv2, const void* Ws2, const void* bs2,
    const void* Wo, const void* bo,
    int* flags, float* wp1, float* bp1, float* wp2, float* bp2, float* woF,
    int* curSB) {
    __shared__ int sf0;
    int t = threadIdx.x;
    if (t == 0) {
        const bf16* pb = (const bf16*)emb;
        int big = 0;
        for (int i = 0; i < 256; i++) {
            float v = __bfloat162float(pb[i]);
            if (!(v > -1.0e6f && v < 1.0e6f)) big++;  // f32-viewed-as-bf16 => ~42% huge/nan
        }
        int f0 = (big <= 8) ? 1 : 0;
        int nz = 0;
        for (int i = 1; i < 256; i += 2) nz += (ei[i] != 0) ? 1 : 0;
        flags[0] = f0;
        flags[1] = (nz == 0) ? 1 : 0;     // int64 => odd int32 words all zero
        sf0 = f0;
    }
    __syncthreads();
    int isbf = sf0;
    for (int i = t; i < 1024; i += 256) {
        wp1[i]        = ldf(Wq1, i, isbf);
        wp1[1024 + i] = ldf(Wk1, i, isbf);
        wp1[2048 + i] = ldf(Wv1, i, isbf);
        wp1[3072 + i] = ldf(Ws1, i, isbf);
    }
    for (int i = t; i < 512; i += 256) {
        wp2[i]        = ldf(Wq2, i, isbf);
        wp2[512 + i]  = ldf(Wk2, i, isbf);
        wp2[1024 + i] = ldf(Wv2, i, isbf);
        wp2[1536 + i] = ldf(Ws2, i, isbf);
    }
    if (t < 32) {
        bp1[t] = ldf(bq1, t, isbf); bp1[32 + t] = ldf(bk1, t, isbf);
        bp1[64 + t] = ldf(bv1, t, isbf); bp1[96 + t] = ldf(bs1, t, isbf);
        woF[t] = ldf(Wo, t, isbf);
    }
    if (t < 16) {
        bp2[t] = ldf(bq2, t, isbf); bp2[16 + t] = ldf(bk2, t, isbf);
        bp2[32 + t] = ldf(bv2, t, isbf); bp2[48 + t] = ldf(bs2, t, isbf);
    }
    if (t < 2) woF[32 + t] = ldf(bo, t, isbf);
    curSB[t] = 0;   // 256 entries, 256 threads
}

// ---------- Pass A: LDS-coalesced radix into 196 super-buckets ----------
__global__ void radix_a(const int* __restrict__ ei, const int* __restrict__ flags,
                        int* __restrict__ curSB, uint* __restrict__ pairsSB) {
    __shared__ int cnt[NSBP];
    __shared__ int excl[NSBP];
    __shared__ int gbase[NSBP];
    __shared__ uint sVal[RND];
    __shared__ unsigned char sSb[RND];
    const int is64 = flags[1];
    int t = threadIdx.x;
    for (int i = t; i < NSBP; i += 256) cnt[i] = 0;
    __syncthreads();
    long base = (long)blockIdx.x * RND;

    int mySb[16]; int myRank[16]; uint myPk[16];
#pragma unroll
    for (int r = 0; r < 16; r++) {
        long e = base + r * 256 + t;
        mySb[r] = -1;
        if (e < N_EDGES_C) {
            int d = ldidx(ei, (long)N_EDGES_C + e, is64);
            int s = ldidx(ei, e, is64);
            int sb = d >> 9;
            myPk[r] = (uint)s | ((uint)(d & 511) << 17);
            myRank[r] = atomicAdd(&cnt[sb], 1);
            mySb[r] = sb;
        }
    }
    __syncthreads();
    if (t == 0) {
        int o = 0;
        for (int i = 0; i < NSBP; i++) { excl[i] = o; o += cnt[i]; }
    }
    __syncthreads();
#pragma unroll
    for (int r = 0; r < 16; r++) {
        if (mySb[r] >= 0) {
            int pos = excl[mySb[r]] + myRank[r];
            sVal[pos] = myPk[r];
            sSb[pos] = (unsigned char)mySb[r];
        }
    }
    __syncthreads();
    for (int i = t; i < NSBP; i += 256)
        gbase[i] = (cnt[i] > 0) ? atomicAdd(&curSB[i], cnt[i]) : 0;
    __syncthreads();
    int tot = excl[NSBP - 1] + cnt[NSBP - 1];
    for (int i = t; i < tot; i += 256) {   // consecutive i in a run -> consecutive global addr
        int sb = sSb[i];
        int gp = gbase[sb] + (i - excl[sb]);
        if (gp < SBCAP)
            pairsSB[(size_t)sb * SBCAP + gp] = sVal[i];
    }
}

// ---------- Pass B: per-SB CSR build (512 dsts) + degree-bin histogram ----------
__global__ void radix_b(const int* __restrict__ curSB, const uint* __restrict__ pairsSB,
                        int* __restrict__ esrc,
                        int* __restrict__ rowbeg, int* __restrict__ rowend,
                        int* __restrict__ cntBins) {
    __shared__ uint sP[SBCAP];                 // 40 KB
    __shared__ int dcnt[512], dexcl[512], dcur[512];
    __shared__ int hbin[NBIN];
    int sb = blockIdx.x;
    int t = threadIdx.x;
    int n = min(curSB[sb], SBCAP);
    for (int i = t; i < 512; i += 256) { dcnt[i] = 0; dcur[i] = 0; }
    if (t < NBIN) hbin[t] = 0;
    __syncthreads();
    for (int i = t; i < n; i += 256) {
        uint pk = pairsSB[(size_t)sb * SBCAP + i];
        sP[i] = pk;
        atomicAdd(&dcnt[(pk >> 17) & 511], 1);
    }
    __syncthreads();
    if (t == 0) {
        int o = 0;
        for (int j = 0; j < 512; j++) { dexcl[j] = o; o += dcnt[j]; }
    }
    __syncthreads();
    const int EB = sb * SBCAP;
    for (int j = t; j < 512; j += 256) {
        int dst = sb * 512 + j;
        if (dst < N_NODES) {
            rowbeg[dst] = EB + dexcl[j];
            rowend[dst] = EB + dexcl[j] + dcnt[j];
            atomicAdd(&hbin[min(dcnt[j], NBIN - 1)], 1);   // degree histogram (LDS)
        }
    }
    for (int i = t; i < n; i += 256) {
        uint pk = sP[i];
        int j = (pk >> 17) & 511;
        int p = dexcl[j] + atomicAdd(&dcur[j], 1);
        esrc[EB + p] = (int)(pk & 0x1FFFF);
    }
    __syncthreads();
    if (t < NBIN) cntBins[t * NSB + sb] = hbin[t];   // bin-major
}

// ---------- single-block exclusive scan over cntBins (12544 ints, in place) ----------
__global__ void scan_all(int* __restrict__ x) {
    __shared__ int buf[CNT_N];     // 50 KB
    __shared__ int part[1024];
    int t = threadIdx.x;
    for (int i = t; i < CNT_N; i += 1024) buf[i] = x[i];
    __syncthreads();
    const int C = (CNT_N + 1023) / 1024;   // 13
    int lo = t * C, hi = min(lo + C, CNT_N);
    int sum = 0;
    for (int i = lo; i < hi; i++) sum += buf[i];
    int v = sum;
    part[t] = v;
    __syncthreads();
    for (int off = 1; off < 1024; off <<= 1) {
        int u = (t >= off) ? part[t - off] : 0;
        __syncthreads();
        part[t] += u;
        __syncthreads();
    }
    int run = part[t] - v;   // exclusive base for this thread's range
    for (int i = lo; i < hi; i++) { int val = buf[i]; buf[i] = run; run += val; }
    __syncthreads();
    for (int i = t; i < CNT_N; i += 1024) x[i] = buf[i];
}

// ---------- perm scatter (196 blocks x 512 threads, matches radix_b block structure) ----------
__global__ void perm_scatter3(const int* __restrict__ rowbeg, const int* __restrict__ rowend,
                              int* __restrict__ basearr, int* __restrict__ perm) {
    __shared__ int cur[NBIN];
    int t = threadIdx.x, sb = blockIdx.x;
    if (t < NBIN) cur[t] = 0;
    __syncthreads();
    int i = sb * 512 + t;
    if (i < N_NODES) {
        int d = min(rowend[i] - rowbeg[i], NBIN - 1);
        int r = atomicAdd(&cur[d], 1);   // LDS atomic
        perm[basearr[d * NSB + sb] + r] = i;
    }
}

// ---------- node linears (block-uniform runtime dtype branch; kv packed bf16 out) ----------
template <int DOUT, bool RUNTIME_DTYPE>
__global__ void node_linear(const void* __restrict__ X,       // [N,32] bf16 or f32
                            const float* __restrict__ wpack,  // [4][32][DOUT] f32
                            const float* __restrict__ bpack,  // [4][DOUT] f32
                            const int* __restrict__ flags,
                            float* __restrict__ q, ushort* __restrict__ kvb,
                            float* __restrict__ s) {
    const int TPN = DOUT / 4;     // threads per node (8 or 4)
    const int NPB = 256 / TPN;    // nodes per block (32 or 64)
    const int W_ELEMS = 4 * 32 * DOUT;
    __shared__ float sW[W_ELEMS];
    __shared__ float sb[4 * DOUT];
    __shared__ float sX[NPB * 36];  // pad stride 36 (16B-aligned, conflict-free)

    const float4* wp4 = (const float4*)wpack;
    float4* sW4 = (float4*)sW;
    for (int i = threadIdx.x; i < W_ELEMS / 4; i += 256) sW4[i] = wp4[i];
    if (threadIdx.x < 4 * DOUT) sb[threadIdx.x] = bpack[threadIdx.x];
    const int base = blockIdx.x * NPB * 32;
    bool useBf = RUNTIME_DTYPE && (flags[0] != 0);   // block-uniform
    if (useBf) {
        for (int i = threadIdx.x; i < NPB * 32; i += 256) {
            int g = base + i;
            float xv = (g < N_NODES * 32) ? __bfloat162float(((const bf16*)X)[g]) : 0.0f;
            sX[(i >> 5) * 36 + (i & 31)] = xv;
        }
    } else {
        for (int i = threadIdx.x; i < NPB * 32; i += 256) {
            int g = base + i;
            sX[(i >> 5) * 36 + (i & 31)] = (g < N_NODES * 32) ? ((const float*)X)[g] : 0.0f;
        }
    }
    __syncthreads();

    int l = threadIdx.x / TPN;
    int c4 = (threadIdx.x % TPN) * 4;
    int n = blockIdx.x * NPB + l;
    if (n >= N_NODES) return;

    float xr[32];
#pragma unroll
    for (int j = 0; j < 8; j++) {
        float4 t = *(const float4*)&sX[l * 36 + 4 * j];
        xr[4 * j] = t.x; xr[4 * j + 1] = t.y; xr[4 * j + 2] = t.z; xr[4 * j + 3] = t.w;
    }
    float acc[4][4];
#pragma unroll
    for (int m = 0; m < 4; m++)
#pragma unroll
        for (int j = 0; j < 4; j++) acc[m][j] = sb[m * DOUT + c4 + j];

#pragma unroll
    for (int t = 0; t < 32; t++) {
#pragma unroll
        for (int m = 0; m < 4; m++) {
            float4 w = *(const float4*)&sW[(m * 32 + t) * DOUT + c4];
            acc[m][0] += xr[t] * w.x;
            acc[m][1] += xr[t] * w.y;
            acc[m][2] += xr[t] * w.z;
            acc[m][3] += xr[t] * w.w;
        }
    }
    size_t o = (size_t)n * DOUT + c4;
    *(float4*)&q[o] = make_float4(acc[0][0], acc[0][1], acc[0][2], acc[0][3]);
    *(float4*)&s[o] = make_float4(acc[3][0], acc[3][1], acc[3][2], acc[3][3]);
    size_t okv = (size_t)n * 2 * DOUT + c4;
    ushort4 kp = make_ushort4(bfb(acc[1][0]), bfb(acc[1][1]), bfb(acc[1][2]), bfb(acc[1][3]));
    ushort4 vp = make_ushort4(bfb(acc[2][0]), bfb(acc[2][1]), bfb(acc[2][2]), bfb(acc[2][3]));
    *(ushort4*)&kvb[okv]        = kp;
    *(ushort4*)&kvb[okv + DOUT] = vp;
}

// ---------- fused gather attention: D/8 lanes per dst, uint4 (16B) kv loads ----------
template <int D, bool LAYER2>
__global__ void gather_attn(const int* __restrict__ perm,
                            const int* __restrict__ rowbeg, const int* __restrict__ rowend,
                            const int* __restrict__ esrc,
                            const float* __restrict__ q, const ushort* __restrict__ kvb,
                            const float* __restrict__ s,
                            const float* __restrict__ woF,  // [32]=Wo, [32..33]=bo (f32)
                            const int* __restrict__ flags,
                            float* __restrict__ h1o, void* __restrict__ out) {
    const int LPD = D / 8;   // lanes per dst (4 or 2)
    const int G = 64 / LPD;  // dst groups per wave (16 or 32)
    int lane = threadIdx.x & 63;
    int wave = (blockIdx.x * blockDim.x + threadIdx.x) >> 6;
    int g = lane / LPD;
    int c = lane % LPD;      // dims 8c..8c+7
    int idx = wave * G + g;
    if (idx >= N_NODES) return;  // uniform within a group; shfl stays in-group
    int dst = perm[idx];         // degree-sorted: groups in wave have ~equal degree

    const float rsq = (D == 32) ? 0.17677669529663689f : 0.25f;  // 1/sqrt(D)
    float4 qa = *(const float4*)(q + (size_t)dst * D + 8 * c);
    float4 qb = *(const float4*)(q + (size_t)dst * D + 8 * c + 4);
    int beg = rowbeg[dst], end = rowend[dst];

    const char* kvbase = (const char*)kvb;
    const int ROW = 4 * D;            // row bytes: [k bf16 x D | v bf16 x D]
    const int koff = 16 * c;          // 8 dims x 2B
    const int voff = 2 * D + 16 * c;

    float sum0 = 0.f, sum1 = 0.f;
    float a0[8] = {0,0,0,0,0,0,0,0};
    float a1[8] = {0,0,0,0,0,0,0,0};

    // 2-deep software pipeline, unroll x2
    int sn0 = (beg < end) ? esrc[beg] : 0;
    int sn1 = (beg + 1 < end) ? esrc[beg + 1] : 0;
    const char* pa = kvbase + (size_t)sn0 * ROW;
    const char* pb = kvbase + (size_t)sn1 * ROW;
    uint4 kau = *(const uint4*)(pa + koff), vau = *(const uint4*)(pa + voff);
    uint4 kbu = *(const uint4*)(pb + koff), vbu = *(const uint4*)(pb + voff);

    for (int e = beg; e < end; e += 2) {
        uint4 kA = kau, vA = vau, kB = kbu, vB = vbu;
        if (e + 2 < end) {
            const char* p = kvbase + (size_t)esrc[e + 2] * ROW;
            kau = *(const uint4*)(p + koff); vau = *(const uint4*)(p + voff);
        }
        if (e + 3 < end) {
            const char* p = kvbase + (size_t)esrc[e + 3] * ROW;
            kbu = *(const uint4*)(p + koff); vbu = *(const uint4*)(p + voff);
        }
        float pd = qa.x * bl(kA.x) + qa.y * bh(kA.x) + qa.z * bl(kA.y) + qa.w * bh(kA.y)
                 + qb.x * bl(kA.z) + qb.y * bh(kA.z) + qb.z * bl(kA.w) + qb.w * bh(kA.w);
#pragma unroll
        for (int m = LPD / 2; m >= 1; m >>= 1) pd += __shfl_xor(pd, m, LPD);
        float ex = __expf(fminf(fmaxf(pd * rsq, -80.0f), 80.0f));
        sum0 += ex;
        a0[0] += bl(vA.x) * ex; a0[1] += bh(vA.x) * ex;
        a0[2] += bl(vA.y) * ex; a0[3] += bh(vA.y) * ex;
        a0[4] += bl(vA.z) * ex; a0[5] += bh(vA.z) * ex;
        a0[6] += bl(vA.w) * ex; a0[7] += bh(vA.w) * ex;
        if (e + 1 < end) {
            float pd1 = qa.x * bl(kB.x) + qa.y * bh(kB.x) + qa.z * bl(kB.y) + qa.w * bh(kB.y)
                      + qb.x * bl(kB.z) + qb.y * bh(kB.z) + qb.z * bl(kB.w) + qb.w * bh(kB.w);
#pragma unroll
            for (int m = LPD / 2; m >= 1; m >>= 1) pd1 += __shfl_xor(pd1, m, LPD);
            float ex1 = __expf(fminf(fmaxf(pd1 * rsq, -80.0f), 80.0f));
            sum1 += ex1;
            a1[0] += bl(vB.x) * ex1; a1[1] += bh(vB.x) * ex1;
            a1[2] += bl(vB.y) * ex1; a1[3] += bh(vB.y) * ex1;
            a1[4] += bl(vB.z) * ex1; a1[5] += bh(vB.z) * ex1;
            a1[6] += bl(vB.w) * ex1; a1[7] += bh(vB.w) * ex1;
        }
    }
    float inv = 1.0f / (sum0 + sum1 + 1e-16f);
    float4 sa = *(const float4*)(s + (size_t)dst * D + 8 * c);
    float4 sb2 = *(const float4*)(s + (size_t)dst * D + 8 * c + 4);
    float h[8];
    h[0] = (a0[0] + a1[0]) * inv + sa.x;  h[1] = (a0[1] + a1[1]) * inv + sa.y;
    h[2] = (a0[2] + a1[2]) * inv + sa.z;  h[3] = (a0[3] + a1[3]) * inv + sa.w;
    h[4] = (a0[4] + a1[4]) * inv + sb2.x; h[5] = (a0[5] + a1[5]) * inv + sb2.y;
    h[6] = (a0[6] + a1[6]) * inv + sb2.z; h[7] = (a0[7] + a1[7]) * inv + sb2.w;
#pragma unroll
    for (int j = 0; j < 8; j++) h[j] = h[j] > 0.0f ? h[j] : 0.0f;

    if (!LAYER2) {
        *(float4*)(h1o + (size_t)dst * D + 8 * c)     = make_float4(h[0], h[1], h[2], h[3]);
        *(float4*)(h1o + (size_t)dst * D + 8 * c + 4) = make_float4(h[4], h[5], h[6], h[7]);
    } else {
        float p0 = 0.f, p1 = 0.f;
#pragma unroll
        for (int j = 0; j < 8; j++) {
            p0 += h[j] * woF[(8 * c + j) * 2 + 0];
            p1 += h[j] * woF[(8 * c + j) * 2 + 1];
        }
#pragma unroll
        for (int m = LPD / 2; m >= 1; m >>= 1) {
            p0 += __shfl_xor(p0, m, LPD);
            p1 += __shfl_xor(p1, m, LPD);
        }
        if (c == 0) {
            float o0 = p0 + woF[32];
            float o1 = p1 + woF[33];
            if (flags[0]) {
                ((bf16*)out)[dst * 2 + 0] = __float2bfloat16(o0);
                ((bf16*)out)[dst * 2 + 1] = __float2bfloat16(o1);
            } else {
                ((float*)out)[dst * 2 + 0] = o0;
                ((float*)out)[dst * 2 + 1] = o1;
            }
        }
    }
}

extern "C" void kernel_launch(void* const* d_in, const int* in_sizes, int n_in,
                              void* d_out, int out_size, void* d_ws, size_t ws_size,
                              hipStream_t stream) {
    const int* ei  = (const int*)d_in[0];
    const void* emb = d_in[1];
    const void *Wq1 = d_in[2],  *bq1 = d_in[3];
    const void *Wk1 = d_in[4],  *bk1 = d_in[5];
    const void *Wv1 = d_in[6],  *bv1 = d_in[7];
    const void *Ws1 = d_in[8],  *bs1 = d_in[9];
    const void *Wq2 = d_in[10], *bq2 = d_in[11];
    const void *Wk2 = d_in[12], *bk2 = d_in[13];
    const void *Wv2 = d_in[14], *bv2 = d_in[15];
    const void *Ws2 = d_in[16], *bs2 = d_in[17];
    const void *Wo  = d_in[18], *bo  = d_in[19];

    // Workspace layout (floats). pairsSB aliases q (dead after radix_b).
    const size_t ND = (size_t)N_NODES * 32;
    const size_t SBTOT = (size_t)NSB * SBCAP;      // 2,007,040
    float* base   = (float*)d_ws;
    int*   flags  = (int*)base;                    // 64
    float* wp1    = base + 64;                     // 4096
    float* bp1    = wp1 + 4096;                    // 128
    float* wp2    = bp1 + 128;                     // 2048
    float* bp2    = wp2 + 2048;                    // 64
    float* woF    = bp2 + 64;                      // 64
    int*   curSB  = (int*)(woF + 64);              // 256
    int*   cnt    = curSB + 256;                   // CNT_N (12544) -> pad 12800
    int*   rowbeg = cnt + 12800;                   // N_NODES
    int*   rowend = rowbeg + N_NODES;              // N_NODES
    int*   perm   = rowend + N_NODES;              // N_NODES
    float* uni    = (float*)(perm + N_NODES);      // union start
    uint*  pairsSB = (uint*)uni;                   // SBTOT uints (8 MB, alias q)
    float* q      = uni;                           // ND
    float* s      = uni + ND;                      // ND
    ushort* kvb   = (ushort*)(uni + 2 * ND);       // 2*ND ushorts = ND floats
    float* h1     = uni + 3 * ND;                  // ND
    int*   esrc   = (int*)(uni + 4 * ND);          // SBTOT ints (8 MB)
    // total ~ 62 MB

    const int B = 256;
    const int gNL32   = (N_NODES + 31) / 32;           // 3125 (NPB=32)
    const int gNL16   = (N_NODES + 63) / 64;           // 1563 (NPB=64)
    const int gGat32  = ((N_NODES + 15) / 16 * 64 + B - 1) / B;  // G=16 -> 1563
    const int gGat16  = ((N_NODES + 31) / 32 * 64 + B - 1) / B;  // G=32 -> 782
    const int gRadA   = (N_EDGES_C + RND - 1) / RND;   // 391

    // 1: setup (detect + cast params + zero curSB)
    setup_kernel<<<1, B, 0, stream>>>(emb, ei,
        Wq1, bq1, Wk1, bk1, Wv1, bv1, Ws1, bs1,
        Wq2, bq2, Wk2, bk2, Wv2, bv2, Ws2, bs2, Wo, bo,
        flags, wp1, bp1, wp2, bp2, woF, curSB);

    // 2-3: CSR build via LDS-coalesced 2-level radix (+ fused degree histogram)
    radix_a<<<gRadA, B, 0, stream>>>(ei, flags, curSB, pairsSB);
    radix_b<<<NSB, B, 0, stream>>>(curSB, pairsSB, esrc, rowbeg, rowend, cnt);

    // 4-5: degree-sorted dst permutation (single-block scan + LDS-rank scatter)
    scan_all<<<1, 1024, 0, stream>>>(cnt);
    perm_scatter3<<<NSB, 512, 0, stream>>>(rowbeg, rowend, cnt, perm);

    // 6-7: Layer 1 (32 -> 32)
    node_linear<32, true><<<gNL32, B, 0, stream>>>(emb, wp1, bp1, flags, q, kvb, s);
    gather_attn<32, false><<<gGat32, B, 0, stream>>>(
        perm, rowbeg, rowend, esrc, q, kvb, s, woF, flags, h1, nullptr);

    // 8-9: Layer 2 (32 -> 16) + output linear
    node_linear<16, false><<<gNL16, B, 0, stream>>>(h1, wp2, bp2, flags, q, kvb, s);
    gather_attn<16, true><<<gGat16, B, 0, stream>>>(
        perm, rowbeg, rowend, esrc, q, kvb, s, woF, flags, nullptr, d_out);
}

// Round 16
// 285.197 us; speedup vs baseline: 2.8976x; 1.0372x over previous
//
#include <hip/hip_runtime.h>
#include <hip/hip_bf16.h>

typedef __hip_bfloat16 bf16;
typedef unsigned int uint;
typedef unsigned short ushort;

#define N_NODES 100000
#define N_EDGES_C 1600000
#define NSB 196            // super-buckets: dst>>9 (512 dsts each); 196*512=100352
#define NSBP 200           // padded counter array size
#define SBCAP 10240        // per-SB region capacity (mean 8163, +23 sigma)
#define RND 2048           // edges per radix_a block (782 blocks, ~3/CU)
#define EPB (RND / 256)    // 8 edges per thread
#define NBIN 64            // degree bins (Poisson(16): max deg ~50; cap only affects balance)
#define CNT_N (NBIN * NSB) // 12544

// ---------- runtime dtype helpers (flags[0]=floats-are-bf16, flags[1]=indices-are-int64) ----------
__device__ __forceinline__ float ldf(const void* p, long i, int isbf) {
    return isbf ? __bfloat162float(((const bf16*)p)[i]) : ((const float*)p)[i];
}
__device__ __forceinline__ int ldidx(const int* ei, long pos, int is64) {
    return is64 ? ei[2 * pos] : ei[pos];   // int64 LE: low word at 2*pos
}
__device__ __forceinline__ ushort bfb(float x) {   // f32 -> bf16 bits (RNE)
    bf16 h = __float2bfloat16(x);
    return *(ushort*)&h;
}
__device__ __forceinline__ float bl(uint u) { return __uint_as_float(u << 16); }        // low bf16
__device__ __forceinline__ float bh(uint u) { return __uint_as_float(u & 0xFFFF0000u); } // high bf16

// ---------- setup: detect dtypes + cast params + zero curSB (one launch) ----------
__global__ void setup_kernel(
    const void* emb, const int* ei,
    const void* Wq1, const void* bq1, const void* Wk1, const void* bk1,
    const void* Wv1, const void* bv1, const void* Ws1, const void* bs1,
    const void* Wq2, const void* bq2, const void* Wk2, const void* bk2,
    const void* Wv2, const void* bv2, const void* Ws2, const void* bs2,
    const void* Wo, const void* bo,
    int* flags, float* wp1, float* bp1, float* wp2, float* bp2, float* woF,
    int* curSB) {
    __shared__ int sf0;
    int t = threadIdx.x;
    if (t == 0) {
        const bf16* pb = (const bf16*)emb;
        int big = 0;
        for (int i = 0; i < 256; i++) {
            float v = __bfloat162float(pb[i]);
            if (!(v > -1.0e6f && v < 1.0e6f)) big++;  // f32-viewed-as-bf16 => ~42% huge/nan
        }
        int f0 = (big <= 8) ? 1 : 0;
        int nz = 0;
        for (int i = 1; i < 256; i += 2) nz += (ei[i] != 0) ? 1 : 0;
        flags[0] = f0;
        flags[1] = (nz == 0) ? 1 : 0;     // int64 => odd int32 words all zero
        sf0 = f0;
    }
    __syncthreads();
    int isbf = sf0;
    for (int i = t; i < 1024; i += 256) {
        wp1[i]        = ldf(Wq1, i, isbf);
        wp1[1024 + i] = ldf(Wk1, i, isbf);
        wp1[2048 + i] = ldf(Wv1, i, isbf);
        wp1[3072 + i] = ldf(Ws1, i, isbf);
    }
    for (int i = t; i < 512; i += 256) {
        wp2[i]        = ldf(Wq2, i, isbf);
        wp2[512 + i]  = ldf(Wk2, i, isbf);
        wp2[1024 + i] = ldf(Wv2, i, isbf);
        wp2[1536 + i] = ldf(Ws2, i, isbf);
    }
    if (t < 32) {
        bp1[t] = ldf(bq1, t, isbf); bp1[32 + t] = ldf(bk1, t, isbf);
        bp1[64 + t] = ldf(bv1, t, isbf); bp1[96 + t] = ldf(bs1, t, isbf);
        woF[t] = ldf(Wo, t, isbf);
    }
    if (t < 16) {
        bp2[t] = ldf(bq2, t, isbf); bp2[16 + t] = ldf(bk2, t, isbf);
        bp2[32 + t] = ldf(bv2, t, isbf); bp2[48 + t] = ldf(bs2, t, isbf);
    }
    if (t < 2) woF[32 + t] = ldf(bo, t, isbf);
    curSB[t] = 0;   // 256 entries, 256 threads
}

// ---------- Pass A: LDS-coalesced radix into 196 super-buckets (parallel scan) ----------
__global__ void radix_a(const int* __restrict__ ei, const int* __restrict__ flags,
                        int* __restrict__ curSB, uint* __restrict__ pairsSB) {
    __shared__ int cnt[256];       // NSBP used; padded to 256 for the scan
    __shared__ int excl[256];
    __shared__ int gbase[NSBP];
    __shared__ uint sVal[RND];
    __shared__ unsigned char sSb[RND];
    const int is64 = flags[1];
    int t = threadIdx.x;
    cnt[t] = 0;
    __syncthreads();
    long base = (long)blockIdx.x * RND;

    int mySb[EPB]; int myRank[EPB]; uint myPk[EPB];
#pragma unroll
    for (int r = 0; r < EPB; r++) {
        long e = base + r * 256 + t;
        mySb[r] = -1;
        if (e < N_EDGES_C) {
            int d = ldidx(ei, (long)N_EDGES_C + e, is64);
            int s = ldidx(ei, e, is64);
            int sb = d >> 9;
            myPk[r] = (uint)s | ((uint)(d & 511) << 17);
            myRank[r] = atomicAdd(&cnt[sb], 1);
            mySb[r] = sb;
        }
    }
    __syncthreads();
    // parallel exclusive scan over cnt[0..255] (Hillis-Steele, 8 steps)
    int v = cnt[t];
    excl[t] = v;
    __syncthreads();
    for (int off = 1; off < 256; off <<= 1) {
        int u = (t >= off) ? excl[t - off] : 0;
        __syncthreads();
        excl[t] += u;
        __syncthreads();
    }
    int myExcl = excl[t] - v;   // exclusive
    __syncthreads();
    excl[t] = myExcl;
    __syncthreads();
#pragma unroll
    for (int r = 0; r < EPB; r++) {
        if (mySb[r] >= 0) {
            int pos = excl[mySb[r]] + myRank[r];
            sVal[pos] = myPk[r];
            sSb[pos] = (unsigned char)mySb[r];
        }
    }
    __syncthreads();
    if (t < NSBP)
        gbase[t] = (cnt[t] > 0) ? atomicAdd(&curSB[t], cnt[t]) : 0;
    __syncthreads();
    int tot = excl[NSBP - 1] + cnt[NSBP - 1];
    for (int i = t; i < tot; i += 256) {   // consecutive i in a run -> consecutive global addr
        int sb = sSb[i];
        int gp = gbase[sb] + (i - excl[sb]);
        if (gp < SBCAP)
            pairsSB[(size_t)sb * SBCAP + gp] = sVal[i];
    }
}

// ---------- Pass B: per-SB CSR build (512 dsts, 512 threads, parallel scan) ----------
__global__ void radix_b(const int* __restrict__ curSB, const uint* __restrict__ pairsSB,
                        int* __restrict__ esrc,
                        int* __restrict__ rowbeg, int* __restrict__ rowend,
                        int* __restrict__ cntBins) {
    __shared__ uint sP[SBCAP];                 // 40 KB
    __shared__ int dcnt[512], dexcl[512], dcur[512];
    __shared__ int hbin[NBIN];
    int sb = blockIdx.x;
    int t = threadIdx.x;                       // 0..511
    int n = min(curSB[sb], SBCAP);
    dcnt[t] = 0; dcur[t] = 0;
    if (t < NBIN) hbin[t] = 0;
    __syncthreads();
    for (int i = t; i < n; i += 512) {
        uint pk = pairsSB[(size_t)sb * SBCAP + i];
        sP[i] = pk;
        atomicAdd(&dcnt[(pk >> 17) & 511], 1);
    }
    __syncthreads();
    // parallel exclusive scan over dcnt[0..511] (Hillis-Steele, 9 steps)
    int v = dcnt[t];
    dexcl[t] = v;
    __syncthreads();
    for (int off = 1; off < 512; off <<= 1) {
        int u = (t >= off) ? dexcl[t - off] : 0;
        __syncthreads();
        dexcl[t] += u;
        __syncthreads();
    }
    int myExcl = dexcl[t] - v;
    __syncthreads();
    dexcl[t] = myExcl;
    __syncthreads();
    const int EB = sb * SBCAP;
    int dst = sb * 512 + t;
    if (dst < N_NODES) {
        rowbeg[dst] = EB + dexcl[t];
        rowend[dst] = EB + dexcl[t] + dcnt[t];
        atomicAdd(&hbin[min(dcnt[t], NBIN - 1)], 1);   // degree histogram (LDS)
    }
    for (int i = t; i < n; i += 512) {
        uint pk = sP[i];
        int j = (pk >> 17) & 511;
        int p = dexcl[j] + atomicAdd(&dcur[j], 1);
        esrc[EB + p] = (int)(pk & 0x1FFFF);
    }
    __syncthreads();
    if (t < NBIN) cntBins[t * NSB + sb] = hbin[t];   // bin-major
}

// ---------- single-block exclusive scan over cntBins (12544 ints, in place) ----------
__global__ void scan_all(int* __restrict__ x) {
    __shared__ int buf[CNT_N];     // 50 KB
    __shared__ int part[1024];
    int t = threadIdx.x;
    for (int i = t; i < CNT_N; i += 1024) buf[i] = x[i];
    __syncthreads();
    const int C = (CNT_N + 1023) / 1024;   // 13
    int lo = t * C, hi = min(lo + C, CNT_N);
    int sum = 0;
    for (int i = lo; i < hi; i++) sum += buf[i];
    int v = sum;
    part[t] = v;
    __syncthreads();
    for (int off = 1; off < 1024; off <<= 1) {
        int u = (t >= off) ? part[t - off] : 0;
        __syncthreads();
        part[t] += u;
        __syncthreads();
    }
    int run = part[t] - v;   // exclusive base for this thread's range
    for (int i = lo; i < hi; i++) { int val = buf[i]; buf[i] = run; run += val; }
    __syncthreads();
    for (int i = t; i < CNT_N; i += 1024) x[i] = buf[i];
}

// ---------- perm scatter (196 blocks x 512 threads, matches radix_b block structure) ----------
__global__ void perm_scatter3(const int* __restrict__ rowbeg, const int* __restrict__ rowend,
                              int* __restrict__ basearr, int* __restrict__ perm) {
    __shared__ int cur[NBIN];
    int t = threadIdx.x, sb = blockIdx.x;
    if (t < NBIN) cur[t] = 0;
    __syncthreads();
    int i = sb * 512 + t;
    if (i < N_NODES) {
        int d = min(rowend[i] - rowbeg[i], NBIN - 1);
        int r = atomicAdd(&cur[d], 1);   // LDS atomic
        perm[basearr[d * NSB + sb] + r] = i;
    }
}

// ---------- node linears (block-uniform runtime dtype branch; kv packed bf16 out) ----------
template <int DOUT, bool RUNTIME_DTYPE>
__global__ void node_linear(const void* __restrict__ X,       // [N,32] bf16 or f32
                            const float* __restrict__ wpack,  // [4][32][DOUT] f32
                            const float* __restrict__ bpack,  // [4][DOUT] f32
                            const int* __restrict__ flags,
                            float* __restrict__ q, ushort* __restrict__ kvb,
                            float* __restrict__ s) {
    const int TPN = DOUT / 4;     // threads per node (8 or 4)
    const int NPB = 256 / TPN;    // nodes per block (32 or 64)
    const int W_ELEMS = 4 * 32 * DOUT;
    __shared__ float sW[W_ELEMS];
    __shared__ float sb[4 * DOUT];
    __shared__ float sX[NPB * 36];  // pad stride 36 (16B-aligned, conflict-free)

    const float4* wp4 = (const float4*)wpack;
    float4* sW4 = (float4*)sW;
    for (int i = threadIdx.x; i < W_ELEMS / 4; i += 256) sW4[i] = wp4[i];
    if (threadIdx.x < 4 * DOUT) sb[threadIdx.x] = bpack[threadIdx.x];
    const int base = blockIdx.x * NPB * 32;
    bool useBf = RUNTIME_DTYPE && (flags[0] != 0);   // block-uniform
    if (useBf) {
        for (int i = threadIdx.x; i < NPB * 32; i += 256) {
            int g = base + i;
            float xv = (g < N_NODES * 32) ? __bfloat162float(((const bf16*)X)[g]) : 0.0f;
            sX[(i >> 5) * 36 + (i & 31)] = xv;
        }
    } else {
        for (int i = threadIdx.x; i < NPB * 32; i += 256) {
            int g = base + i;
            sX[(i >> 5) * 36 + (i & 31)] = (g < N_NODES * 32) ? ((const float*)X)[g] : 0.0f;
        }
    }
    __syncthreads();

    int l = threadIdx.x / TPN;
    int c4 = (threadIdx.x % TPN) * 4;
    int n = blockIdx.x * NPB + l;
    if (n >= N_NODES) return;

    float xr[32];
#pragma unroll
    for (int j = 0; j < 8; j++) {
        float4 t = *(const float4*)&sX[l * 36 + 4 * j];
        xr[4 * j] = t.x; xr[4 * j + 1] = t.y; xr[4 * j + 2] = t.z; xr[4 * j + 3] = t.w;
    }
    float acc[4][4];
#pragma unroll
    for (int m = 0; m < 4; m++)
#pragma unroll
        for (int j = 0; j < 4; j++) acc[m][j] = sb[m * DOUT + c4 + j];

#pragma unroll
    for (int t = 0; t < 32; t++) {
#pragma unroll
        for (int m = 0; m < 4; m++) {
            float4 w = *(const float4*)&sW[(m * 32 + t) * DOUT + c4];
            acc[m][0] += xr[t] * w.x;
            acc[m][1] += xr[t] * w.y;
            acc[m][2] += xr[t] * w.z;
            acc[m][3] += xr[t] * w.w;
        }
    }
    size_t o = (size_t)n * DOUT + c4;
    *(float4*)&q[o] = make_float4(acc[0][0], acc[0][1], acc[0][2], acc[0][3]);
    *(float4*)&s[o] = make_float4(acc[3][0], acc[3][1], acc[3][2], acc[3][3]);
    size_t okv = (size_t)n * 2 * DOUT + c4;
    ushort4 kp = make_ushort4(bfb(acc[1][0]), bfb(acc[1][1]), bfb(acc[1][2]), bfb(acc[1][3]));
    ushort4 vp = make_ushort4(bfb(acc[2][0]), bfb(acc[2][1]), bfb(acc[2][2]), bfb(acc[2][3]));
    *(ushort4*)&kvb[okv]        = kp;
    *(ushort4*)&kvb[okv + DOUT] = vp;
}

// ---------- fused gather attention: D/8 lanes per dst, uint4 (16B) kv loads ----------
template <int D, bool LAYER2>
__global__ void gather_attn(const int* __restrict__ perm,
                            const int* __restrict__ rowbeg, const int* __restrict__ rowend,
                            const int* __restrict__ esrc,
                            const float* __restrict__ q, const ushort* __restrict__ kvb,
                            const float* __restrict__ s,
                            const float* __restrict__ woF,  // [32]=Wo, [32..33]=bo (f32)
                            const int* __restrict__ flags,
                            float* __restrict__ h1o, void* __restrict__ out) {
    const int LPD = D / 8;   // lanes per dst (4 or 2)
    const int G = 64 / LPD;  // dst groups per wave (16 or 32)
    int lane = threadIdx.x & 63;
    int wave = (blockIdx.x * blockDim.x + threadIdx.x) >> 6;
    int g = lane / LPD;
    int c = lane % LPD;      // dims 8c..8c+7
    int idx = wave * G + g;
    if (idx >= N_NODES) return;  // uniform within a group; shfl stays in-group
    int dst = perm[idx];         // degree-sorted: groups in wave have ~equal degree

    const float rsq = (D == 32) ? 0.17677669529663689f : 0.25f;  // 1/sqrt(D)
    float4 qa = *(const float4*)(q + (size_t)dst * D + 8 * c);
    float4 qb = *(const float4*)(q + (size_t)dst * D + 8 * c + 4);
    int beg = rowbeg[dst], end = rowend[dst];

    const char* kvbase = (const char*)kvb;
    const int ROW = 4 * D;            // row bytes: [k bf16 x D | v bf16 x D]
    const int koff = 16 * c;          // 8 dims x 2B
    const int voff = 2 * D + 16 * c;

    float sum0 = 0.f, sum1 = 0.f;
    float a0[8] = {0,0,0,0,0,0,0,0};
    float a1[8] = {0,0,0,0,0,0,0,0};

    // 2-deep software pipeline, unroll x2
    int sn0 = (beg < end) ? esrc[beg] : 0;
    int sn1 = (beg + 1 < end) ? esrc[beg + 1] : 0;
    const char* pa = kvbase + (size_t)sn0 * ROW;
    const char* pb = kvbase + (size_t)sn1 * ROW;
    uint4 kau = *(const uint4*)(pa + koff), vau = *(const uint4*)(pa + voff);
    uint4 kbu = *(const uint4*)(pb + koff), vbu = *(const uint4*)(pb + voff);

    for (int e = beg; e < end; e += 2) {
        uint4 kA = kau, vA = vau, kB = kbu, vB = vbu;
        if (e + 2 < end) {
            const char* p = kvbase + (size_t)esrc[e + 2] * ROW;
            kau = *(const uint4*)(p + koff); vau = *(const uint4*)(p + voff);
        }
        if (e + 3 < end) {
            const char* p = kvbase + (size_t)esrc[e + 3] * ROW;
            kbu = *(const uint4*)(p + koff); vbu = *(const uint4*)(p + voff);
        }
        float pd = qa.x * bl(kA.x) + qa.y * bh(kA.x) + qa.z * bl(kA.y) + qa.w * bh(kA.y)
                 + qb.x * bl(kA.z) + qb.y * bh(kA.z) + qb.z * bl(kA.w) + qb.w * bh(kA.w);
#pragma unroll
        for (int m = LPD / 2; m >= 1; m >>= 1) pd += __shfl_xor(pd, m, LPD);
        float ex = __expf(fminf(fmaxf(pd * rsq, -80.0f), 80.0f));
        sum0 += ex;
        a0[0] += bl(vA.x) * ex; a0[1] += bh(vA.x) * ex;
        a0[2] += bl(vA.y) * ex; a0[3] += bh(vA.y) * ex;
        a0[4] += bl(vA.z) * ex; a0[5] += bh(vA.z) * ex;
        a0[6] += bl(vA.w) * ex; a0[7] += bh(vA.w) * ex;
        if (e + 1 < end) {
            float pd1 = qa.x * bl(kB.x) + qa.y * bh(kB.x) + qa.z * bl(kB.y) + qa.w * bh(kB.y)
                      + qb.x * bl(kB.z) + qb.y * bh(kB.z) + qb.z * bl(kB.w) + qb.w * bh(kB.w);
#pragma unroll
            for (int m = LPD / 2; m >= 1; m >>= 1) pd1 += __shfl_xor(pd1, m, LPD);
            float ex1 = __expf(fminf(fmaxf(pd1 * rsq, -80.0f), 80.0f));
            sum1 += ex1;
            a1[0] += bl(vB.x) * ex1; a1[1] += bh(vB.x) * ex1;
            a1[2] += bl(vB.y) * ex1; a1[3] += bh(vB.y) * ex1;
            a1[4] += bl(vB.z) * ex1; a1[5] += bh(vB.z) * ex1;
            a1[6] += bl(vB.w) * ex1; a1[7] += bh(vB.w) * ex1;
        }
    }
    float inv = 1.0f / (sum0 + sum1 + 1e-16f);
    float4 sa = *(const float4*)(s + (size_t)dst * D + 8 * c);
    float4 sb2 = *(const float4*)(s + (size_t)dst * D + 8 * c + 4);
    float h[8];
    h[0] = (a0[0] + a1[0]) * inv + sa.x;  h[1] = (a0[1] + a1[1]) * inv + sa.y;
    h[2] = (a0[2] + a1[2]) * inv + sa.z;  h[3] = (a0[3] + a1[3]) * inv + sa.w;
    h[4] = (a0[4] + a1[4]) * inv + sb2.x; h[5] = (a0[5] + a1[5]) * inv + sb2.y;
    h[6] = (a0[6] + a1[6]) * inv + sb2.z; h[7] = (a0[7] + a1[7]) * inv + sb2.w;
#pragma unroll
    for (int j = 0; j < 8; j++) h[j] = h[j] > 0.0f ? h[j] : 0.0f;

    if (!LAYER2) {
        *(float4*)(h1o + (size_t)dst * D + 8 * c)     = make_float4(h[0], h[1], h[2], h[3]);
        *(float4*)(h1o + (size_t)dst * D + 8 * c + 4) = make_float4(h[4], h[5], h[6], h[7]);
    } else {
        float p0 = 0.f, p1 = 0.f;
#pragma unroll
        for (int j = 0; j < 8; j++) {
            p0 += h[j] * woF[(8 * c + j) * 2 + 0];
            p1 += h[j] * woF[(8 * c + j) * 2 + 1];
        }
#pragma unroll
        for (int m = LPD / 2; m >= 1; m >>= 1) {
            p0 += __shfl_xor(p0, m, LPD);
            p1 += __shfl_xor(p1, m, LPD);
        }
        if (c == 0) {
            float o0 = p0 + woF[32];
            float o1 = p1 + woF[33];
            if (flags[0]) {
                ((bf16*)out)[dst * 2 + 0] = __float2bfloat16(o0);
                ((bf16*)out)[dst * 2 + 1] = __float2bfloat16(o1);
            } else {
                ((float*)out)[dst * 2 + 0] = o0;
                ((float*)out)[dst * 2 + 1] = o1;
            }
        }
    }
}

extern "C" void kernel_launch(void* const* d_in, const int* in_sizes, int n_in,
                              void* d_out, int out_size, void* d_ws, size_t ws_size,
                              hipStream_t stream) {
    const int* ei  = (const int*)d_in[0];
    const void* emb = d_in[1];
    const void *Wq1 = d_in[2],  *bq1 = d_in[3];
    const void *Wk1 = d_in[4],  *bk1 = d_in[5];
    const void *Wv1 = d_in[6],  *bv1 = d_in[7];
    const void *Ws1 = d_in[8],  *bs1 = d_in[9];
    const void *Wq2 = d_in[10], *bq2 = d_in[11];
    const void *Wk2 = d_in[12], *bk2 = d_in[13];
    const void *Wv2 = d_in[14], *bv2 = d_in[15];
    const void *Ws2 = d_in[16], *bs2 = d_in[17];
    const void *Wo  = d_in[18], *bo  = d_in[19];

    // Workspace layout (floats). pairsSB aliases q (dead after radix_b).
    const size_t ND = (size_t)N_NODES * 32;
    const size_t SBTOT = (size_t)NSB * SBCAP;      // 2,007,040
    float* base   = (float*)d_ws;
    int*   flags  = (int*)base;                    // 64
    float* wp1    = base + 64;                     // 4096
    float* bp1    = wp1 + 4096;                    // 128
    float* wp2    = bp1 + 128;                     // 2048
    float* bp2    = wp2 + 2048;                    // 64
    float* woF    = bp2 + 64;                      // 64
    int*   curSB  = (int*)(woF + 64);              // 256
    int*   cnt    = curSB + 256;                   // CNT_N (12544) -> pad 12800
    int*   rowbeg = cnt + 12800;                   // N_NODES
    int*   rowend = rowbeg + N_NODES;              // N_NODES
    int*   perm   = rowend + N_NODES;              // N_NODES
    float* uni    = (float*)(perm + N_NODES);      // union start
    uint*  pairsSB = (uint*)uni;                   // SBTOT uints (8 MB, alias q)
    float* q      = uni;                           // ND
    float* s      = uni + ND;                      // ND
    ushort* kvb   = (ushort*)(uni + 2 * ND);       // 2*ND ushorts = ND floats
    float* h1     = uni + 3 * ND;                  // ND
    int*   esrc   = (int*)(uni + 4 * ND);          // SBTOT ints (8 MB)
    // total ~ 62 MB

    const int B = 256;
    const int gNL32   = (N_NODES + 31) / 32;           // 3125 (NPB=32)
    const int gNL16   = (N_NODES + 63) / 64;           // 1563 (NPB=64)
    const int gGat32  = ((N_NODES + 15) / 16 * 64 + B - 1) / B;  // G=16 -> 1563
    const int gGat16  = ((N_NODES + 31) / 32 * 64 + B - 1) / B;  // G=32 -> 782
    const int gRadA   = (N_EDGES_C + RND - 1) / RND;   // 782

    // 1: setup (detect + cast params + zero curSB)
    setup_kernel<<<1, B, 0, stream>>>(emb, ei,
        Wq1, bq1, Wk1, bk1, Wv1, bv1, Ws1, bs1,
        Wq2, bq2, Wk2, bk2, Wv2, bv2, Ws2, bs2, Wo, bo,
        flags, wp1, bp1, wp2, bp2, woF, curSB);

    // 2-3: CSR build via LDS-coalesced 2-level radix (+ fused degree histogram)
    radix_a<<<gRadA, B, 0, stream>>>(ei, flags, curSB, pairsSB);
    radix_b<<<NSB, 512, 0, stream>>>(curSB, pairsSB, esrc, rowbeg, rowend, cnt);

    // 4-5: degree-sorted dst permutation (single-block scan + LDS-rank scatter)
    scan_all<<<1, 1024, 0, stream>>>(cnt);
    perm_scatter3<<<NSB, 512, 0, stream>>>(rowbeg, rowend, cnt, perm);

    // 6-7: Layer 1 (32 -> 32)
    node_linear<32, true><<<gNL32, B, 0, stream>>>(emb, wp1, bp1, flags, q, kvb, s);
    gather_attn<32, false><<<gGat32, B, 0, stream>>>(
        perm, rowbeg, rowend, esrc, q, kvb, s, woF, flags, h1, nullptr);

    // 8-9: Layer 2 (32 -> 16) + output linear
    node_linear<16, false><<<gNL16, B, 0, stream>>>(h1, wp2, bp2, flags, q, kvb, s);
    gather_attn<16, true><<<gGat16, B, 0, stream>>>(
        perm, rowbeg, rowend, esrc, q, kvb, s, woF, flags, nullptr, d_out);
}

// Round 17
// 281.041 us; speedup vs baseline: 2.9405x; 1.0148x over previous
//
#include <hip/hip_runtime.h>
#include <hip/hip_bf16.h>

typedef __hip_bfloat16 bf16;
typedef unsigned int uint;
typedef unsigned short ushort;

#define N_NODES 100000
#define N_EDGES_C 1600000
#define NSB 196            // super-buckets: dst>>9 (512 dsts each); 196*512=100352
#define NSBP 200           // padded counter array size
#define SBCAP 10240        // per-SB region capacity (mean 8163, +23 sigma)
#define RND 2048           // edges per radix_a block (782 blocks, ~3/CU)
#define EPB (RND / 256)    // 8 edges per thread
#define NBIN 64            // degree bins (Poisson(16): max deg ~50; cap only affects balance)
#define CNT_N (NBIN * NSB) // 12544

// ---------- runtime dtype helpers (flags[0]=floats-are-bf16, flags[1]=indices-are-int64) ----------
__device__ __forceinline__ float ldf(const void* p, long i, int isbf) {
    return isbf ? __bfloat162float(((const bf16*)p)[i]) : ((const float*)p)[i];
}
__device__ __forceinline__ int ldidx(const int* ei, long pos, int is64) {
    return is64 ? ei[2 * pos] : ei[pos];   // int64 LE: low word at 2*pos
}
__device__ __forceinline__ ushort bfb(float x) {   // f32 -> bf16 bits (RNE)
    bf16 h = __float2bfloat16(x);
    return *(ushort*)&h;
}
__device__ __forceinline__ float bl(uint u) { return __uint_as_float(u << 16); }        // low bf16
__device__ __forceinline__ float bh(uint u) { return __uint_as_float(u & 0xFFFF0000u); } // high bf16

// ---------- setup: detect dtypes + cast params + zero curSB (one launch) ----------
__global__ void setup_kernel(
    const void* emb, const int* ei,
    const void* Wq1, const void* bq1, const void* Wk1, const void* bk1,
    const void* Wv1, const void* bv1, const void* Ws1, const void* bs1,
    const void* Wq2, const void* bq2, const void* Wk2, const void* bk2,
    const void* Wv2, const void* bv2, const void* Ws2, const void* bs2,
    const void* Wo, const void* bo,
    int* flags, float* wp1, float* bp1, float* wp2, float* bp2, float* woF,
    int* curSB) {
    __shared__ int sf0;
    int t = threadIdx.x;
    if (t == 0) {
        const bf16* pb = (const bf16*)emb;
        int big = 0;
        for (int i = 0; i < 256; i++) {
            float v = __bfloat162float(pb[i]);
            if (!(v > -1.0e6f && v < 1.0e6f)) big++;  // f32-viewed-as-bf16 => ~42% huge/nan
        }
        int f0 = (big <= 8) ? 1 : 0;
        int nz = 0;
        for (int i = 1; i < 256; i += 2) nz += (ei[i] != 0) ? 1 : 0;
        flags[0] = f0;
        flags[1] = (nz == 0) ? 1 : 0;     // int64 => odd int32 words all zero
        sf0 = f0;
    }
    __syncthreads();
    int isbf = sf0;
    for (int i = t; i < 1024; i += 256) {
        wp1[i]        = ldf(Wq1, i, isbf);
        wp1[1024 + i] = ldf(Wk1, i, isbf);
        wp1[2048 + i] = ldf(Wv1, i, isbf);
        wp1[3072 + i] = ldf(Ws1, i, isbf);
    }
    for (int i = t; i < 512; i += 256) {
        wp2[i]        = ldf(Wq2, i, isbf);
        wp2[512 + i]  = ldf(Wk2, i, isbf);
        wp2[1024 + i] = ldf(Wv2, i, isbf);
        wp2[1536 + i] = ldf(Ws2, i, isbf);
    }
    if (t < 32) {
        bp1[t] = ldf(bq1, t, isbf); bp1[32 + t] = ldf(bk1, t, isbf);
        bp1[64 + t] = ldf(bv1, t, isbf); bp1[96 + t] = ldf(bs1, t, isbf);
        woF[t] = ldf(Wo, t, isbf);
    }
    if (t < 16) {
        bp2[t] = ldf(bq2, t, isbf); bp2[16 + t] = ldf(bk2, t, isbf);
        bp2[32 + t] = ldf(bv2, t, isbf); bp2[48 + t] = ldf(bs2, t, isbf);
    }
    if (t < 2) woF[32 + t] = ldf(bo, t, isbf);
    curSB[t] = 0;   // 256 entries, 256 threads
}

// ---------- Pass A: LDS-coalesced radix into 196 super-buckets (parallel scan) ----------
__global__ void radix_a(const int* __restrict__ ei, const int* __restrict__ flags,
                        int* __restrict__ curSB, uint* __restrict__ pairsSB) {
    __shared__ int cnt[256];       // NSBP used; padded to 256 for the scan
    __shared__ int excl[256];
    __shared__ int gbase[NSBP];
    __shared__ uint sVal[RND];
    __shared__ unsigned char sSb[RND];
    const int is64 = flags[1];
    int t = threadIdx.x;
    cnt[t] = 0;
    __syncthreads();
    long base = (long)blockIdx.x * RND;

    int mySb[EPB]; int myRank[EPB]; uint myPk[EPB];
#pragma unroll
    for (int r = 0; r < EPB; r++) {
        long e = base + r * 256 + t;
        mySb[r] = -1;
        if (e < N_EDGES_C) {
            int d = ldidx(ei, (long)N_EDGES_C + e, is64);
            int s = ldidx(ei, e, is64);
            int sb = d >> 9;
            myPk[r] = (uint)s | ((uint)(d & 511) << 17);
            myRank[r] = atomicAdd(&cnt[sb], 1);
            mySb[r] = sb;
        }
    }
    __syncthreads();
    // parallel exclusive scan over cnt[0..255] (Hillis-Steele, 8 steps)
    int v = cnt[t];
    excl[t] = v;
    __syncthreads();
    for (int off = 1; off < 256; off <<= 1) {
        int u = (t >= off) ? excl[t - off] : 0;
        __syncthreads();
        excl[t] += u;
        __syncthreads();
    }
    int myExcl = excl[t] - v;   // exclusive
    __syncthreads();
    excl[t] = myExcl;
    __syncthreads();
#pragma unroll
    for (int r = 0; r < EPB; r++) {
        if (mySb[r] >= 0) {
            int pos = excl[mySb[r]] + myRank[r];
            sVal[pos] = myPk[r];
            sSb[pos] = (unsigned char)mySb[r];
        }
    }
    __syncthreads();
    if (t < NSBP)
        gbase[t] = (cnt[t] > 0) ? atomicAdd(&curSB[t], cnt[t]) : 0;
    __syncthreads();
    int tot = excl[NSBP - 1] + cnt[NSBP - 1];
    for (int i = t; i < tot; i += 256) {   // consecutive i in a run -> consecutive global addr
        int sb = sSb[i];
        int gp = gbase[sb] + (i - excl[sb]);
        if (gp < SBCAP)
            pairsSB[(size_t)sb * SBCAP + gp] = sVal[i];
    }
}

// ---------- Pass B: per-SB CSR build (512 dsts, 512 threads, parallel scan) ----------
__global__ void radix_b(const int* __restrict__ curSB, const uint* __restrict__ pairsSB,
                        int* __restrict__ esrc,
                        int* __restrict__ rowbeg, int* __restrict__ rowend,
                        int* __restrict__ cntBins) {
    __shared__ uint sP[SBCAP];                 // 40 KB
    __shared__ int dcnt[512], dexcl[512], dcur[512];
    __shared__ int hbin[NBIN];
    int sb = blockIdx.x;
    int t = threadIdx.x;                       // 0..511
    int n = min(curSB[sb], SBCAP);
    dcnt[t] = 0; dcur[t] = 0;
    if (t < NBIN) hbin[t] = 0;
    __syncthreads();
    for (int i = t; i < n; i += 512) {
        uint pk = pairsSB[(size_t)sb * SBCAP + i];
        sP[i] = pk;
        atomicAdd(&dcnt[(pk >> 17) & 511], 1);
    }
    __syncthreads();
    // parallel exclusive scan over dcnt[0..511] (Hillis-Steele, 9 steps)
    int v = dcnt[t];
    dexcl[t] = v;
    __syncthreads();
    for (int off = 1; off < 512; off <<= 1) {
        int u = (t >= off) ? dexcl[t - off] : 0;
        __syncthreads();
        dexcl[t] += u;
        __syncthreads();
    }
    int myExcl = dexcl[t] - v;
    __syncthreads();
    dexcl[t] = myExcl;
    __syncthreads();
    const int EB = sb * SBCAP;
    int dst = sb * 512 + t;
    if (dst < N_NODES) {
        rowbeg[dst] = EB + dexcl[t];
        rowend[dst] = EB + dexcl[t] + dcnt[t];
        atomicAdd(&hbin[min(dcnt[t], NBIN - 1)], 1);   // degree histogram (LDS)
    }
    for (int i = t; i < n; i += 512) {
        uint pk = sP[i];
        int j = (pk >> 17) & 511;
        int p = dexcl[j] + atomicAdd(&dcur[j], 1);
        esrc[EB + p] = (int)(pk & 0x1FFFF);
    }
    __syncthreads();
    if (t < NBIN) cntBins[t * NSB + sb] = hbin[t];   // bin-major
}

// ---------- single-block exclusive scan over cntBins (12544 ints, in place) ----------
__global__ void scan_all(int* __restrict__ x) {
    __shared__ int buf[CNT_N];     // 50 KB
    __shared__ int part[1024];
    int t = threadIdx.x;
    for (int i = t; i < CNT_N; i += 1024) buf[i] = x[i];
    __syncthreads();
    const int C = (CNT_N + 1023) / 1024;   // 13
    int lo = t * C, hi = min(lo + C, CNT_N);
    int sum = 0;
    for (int i = lo; i < hi; i++) sum += buf[i];
    int v = sum;
    part[t] = v;
    __syncthreads();
    for (int off = 1; off < 1024; off <<= 1) {
        int u = (t >= off) ? part[t - off] : 0;
        __syncthreads();
        part[t] += u;
        __syncthreads();
    }
    int run = part[t] - v;   // exclusive base for this thread's range
    for (int i = lo; i < hi; i++) { int val = buf[i]; buf[i] = run; run += val; }
    __syncthreads();
    for (int i = t; i < CNT_N; i += 1024) x[i] = buf[i];
}

// ---------- perm scatter (196 blocks x 512 threads, matches radix_b block structure) ----------
__global__ void perm_scatter3(const int* __restrict__ rowbeg, const int* __restrict__ rowend,
                              int* __restrict__ basearr, int* __restrict__ perm) {
    __shared__ int cur[NBIN];
    int t = threadIdx.x, sb = blockIdx.x;
    if (t < NBIN) cur[t] = 0;
    __syncthreads();
    int i = sb * 512 + t;
    if (i < N_NODES) {
        int d = min(rowend[i] - rowbeg[i], NBIN - 1);
        int r = atomicAdd(&cur[d], 1);   // LDS atomic
        perm[basearr[d * NSB + sb] + r] = i;
    }
}

// ---------- node linears (block-uniform runtime dtype branch; kv packed bf16 out) ----------
template <int DOUT, bool RUNTIME_DTYPE>
__global__ void node_linear(const void* __restrict__ X,       // [N,32] bf16 or f32
                            const float* __restrict__ wpack,  // [4][32][DOUT] f32
                            const float* __restrict__ bpack,  // [4][DOUT] f32
                            const int* __restrict__ flags,
                            float* __restrict__ q, ushort* __restrict__ kvb,
                            float* __restrict__ s) {
    const int TPN = DOUT / 4;     // threads per node (8 or 4)
    const int NPB = 256 / TPN;    // nodes per block (32 or 64)
    const int W_ELEMS = 4 * 32 * DOUT;
    __shared__ float sW[W_ELEMS];
    __shared__ float sb[4 * DOUT];
    __shared__ float sX[NPB * 36];  // pad stride 36 (16B-aligned, conflict-free)

    const float4* wp4 = (const float4*)wpack;
    float4* sW4 = (float4*)sW;
    for (int i = threadIdx.x; i < W_ELEMS / 4; i += 256) sW4[i] = wp4[i];
    if (threadIdx.x < 4 * DOUT) sb[threadIdx.x] = bpack[threadIdx.x];
    const int base = blockIdx.x * NPB * 32;
    bool useBf = RUNTIME_DTYPE && (flags[0] != 0);   // block-uniform
    if (useBf) {
        for (int i = threadIdx.x; i < NPB * 32; i += 256) {
            int g = base + i;
            float xv = (g < N_NODES * 32) ? __bfloat162float(((const bf16*)X)[g]) : 0.0f;
            sX[(i >> 5) * 36 + (i & 31)] = xv;
        }
    } else {
        for (int i = threadIdx.x; i < NPB * 32; i += 256) {
            int g = base + i;
            sX[(i >> 5) * 36 + (i & 31)] = (g < N_NODES * 32) ? ((const float*)X)[g] : 0.0f;
        }
    }
    __syncthreads();

    int l = threadIdx.x / TPN;
    int c4 = (threadIdx.x % TPN) * 4;
    int n = blockIdx.x * NPB + l;
    if (n >= N_NODES) return;

    float xr[32];
#pragma unroll
    for (int j = 0; j < 8; j++) {
        float4 t = *(const float4*)&sX[l * 36 + 4 * j];
        xr[4 * j] = t.x; xr[4 * j + 1] = t.y; xr[4 * j + 2] = t.z; xr[4 * j + 3] = t.w;
    }
    float acc[4][4];
#pragma unroll
    for (int m = 0; m < 4; m++)
#pragma unroll
        for (int j = 0; j < 4; j++) acc[m][j] = sb[m * DOUT + c4 + j];

#pragma unroll
    for (int t = 0; t < 32; t++) {
#pragma unroll
        for (int m = 0; m < 4; m++) {
            float4 w = *(const float4*)&sW[(m * 32 + t) * DOUT + c4];
            acc[m][0] += xr[t] * w.x;
            acc[m][1] += xr[t] * w.y;
            acc[m][2] += xr[t] * w.z;
            acc[m][3] += xr[t] * w.w;
        }
    }
    size_t o = (size_t)n * DOUT + c4;
    *(float4*)&q[o] = make_float4(acc[0][0], acc[0][1], acc[0][2], acc[0][3]);
    *(float4*)&s[o] = make_float4(acc[3][0], acc[3][1], acc[3][2], acc[3][3]);
    size_t okv = (size_t)n * 2 * DOUT + c4;
    ushort4 kp = make_ushort4(bfb(acc[1][0]), bfb(acc[1][1]), bfb(acc[1][2]), bfb(acc[1][3]));
    ushort4 vp = make_ushort4(bfb(acc[2][0]), bfb(acc[2][1]), bfb(acc[2][2]), bfb(acc[2][3]));
    *(ushort4*)&kvb[okv]        = kp;
    *(ushort4*)&kvb[okv + DOUT] = vp;
}

// ---------- fused gather attention: D/8 lanes per dst, uint4 kv loads, 4-deep pipeline ----------
// Heavy-degree dsts scheduled FIRST (perm reversed) for better tail packing.
template <int D, bool LAYER2>
__global__ void gather_attn(const int* __restrict__ perm,
                            const int* __restrict__ rowbeg, const int* __restrict__ rowend,
                            const int* __restrict__ esrc,
                            const float* __restrict__ q, const ushort* __restrict__ kvb,
                            const float* __restrict__ s,
                            const float* __restrict__ woF,  // [32]=Wo, [32..33]=bo (f32)
                            const int* __restrict__ flags,
                            float* __restrict__ h1o, void* __restrict__ out) {
    const int LPD = D / 8;   // lanes per dst (4 or 2)
    const int G = 64 / LPD;  // dst groups per wave (16 or 32)
    int lane = threadIdx.x & 63;
    int wave = (blockIdx.x * blockDim.x + threadIdx.x) >> 6;
    int g = lane / LPD;
    int c = lane % LPD;      // dims 8c..8c+7
    int idx = wave * G + g;
    if (idx >= N_NODES) return;  // uniform within a group; shfl stays in-group
    int dst = perm[(N_NODES - 1) - idx];   // descending degree: heavy nodes first

    const float rsq = (D == 32) ? 0.17677669529663689f : 0.25f;  // 1/sqrt(D)
    float4 qa = *(const float4*)(q + (size_t)dst * D + 8 * c);
    float4 qb = *(const float4*)(q + (size_t)dst * D + 8 * c + 4);
    int beg = rowbeg[dst], end = rowend[dst];

    const char* kvbase = (const char*)kvb;
    const int ROW = 4 * D;            // row bytes: [k bf16 x D | v bf16 x D]
    const int koff = 16 * c;          // 8 dims x 2B
    const int voff = 2 * D + 16 * c;

    float sum0 = 0.f, sum1 = 0.f;
    float a0[8] = {0,0,0,0,0,0,0,0};
    float a1[8] = {0,0,0,0,0,0,0,0};

    // 4-deep software pipeline, unroll x4 (2 accumulator sets)
    uint4 kq[4], vq[4];
#pragma unroll
    for (int r = 0; r < 4; r++) {
        int sn = (beg + r < end) ? esrc[beg + r] : 0;
        const char* p = kvbase + (size_t)sn * ROW;
        kq[r] = *(const uint4*)(p + koff);
        vq[r] = *(const uint4*)(p + voff);
    }

    for (int e = beg; e < end; e += 4) {
        uint4 kc[4], vc[4];
#pragma unroll
        for (int r = 0; r < 4; r++) { kc[r] = kq[r]; vc[r] = vq[r]; }
#pragma unroll
        for (int r = 0; r < 4; r++) {
            if (e + 4 + r < end) {
                const char* p = kvbase + (size_t)esrc[e + 4 + r] * ROW;
                kq[r] = *(const uint4*)(p + koff);
                vq[r] = *(const uint4*)(p + voff);
            }
        }
#pragma unroll
        for (int r = 0; r < 4; r++) {
            if (e + r < end) {
                uint4 kA = kc[r], vA = vc[r];
                float pd = qa.x * bl(kA.x) + qa.y * bh(kA.x) + qa.z * bl(kA.y) + qa.w * bh(kA.y)
                         + qb.x * bl(kA.z) + qb.y * bh(kA.z) + qb.z * bl(kA.w) + qb.w * bh(kA.w);
#pragma unroll
                for (int m = LPD / 2; m >= 1; m >>= 1) pd += __shfl_xor(pd, m, LPD);
                float ex = __expf(fminf(fmaxf(pd * rsq, -80.0f), 80.0f));
                if (r & 1) {
                    sum1 += ex;
                    a1[0] += bl(vA.x) * ex; a1[1] += bh(vA.x) * ex;
                    a1[2] += bl(vA.y) * ex; a1[3] += bh(vA.y) * ex;
                    a1[4] += bl(vA.z) * ex; a1[5] += bh(vA.z) * ex;
                    a1[6] += bl(vA.w) * ex; a1[7] += bh(vA.w) * ex;
                } else {
                    sum0 += ex;
                    a0[0] += bl(vA.x) * ex; a0[1] += bh(vA.x) * ex;
                    a0[2] += bl(vA.y) * ex; a0[3] += bh(vA.y) * ex;
                    a0[4] += bl(vA.z) * ex; a0[5] += bh(vA.z) * ex;
                    a0[6] += bl(vA.w) * ex; a0[7] += bh(vA.w) * ex;
                }
            }
        }
    }
    float inv = 1.0f / (sum0 + sum1 + 1e-16f);
    float4 sa = *(const float4*)(s + (size_t)dst * D + 8 * c);
    float4 sb2 = *(const float4*)(s + (size_t)dst * D + 8 * c + 4);
    float h[8];
    h[0] = (a0[0] + a1[0]) * inv + sa.x;  h[1] = (a0[1] + a1[1]) * inv + sa.y;
    h[2] = (a0[2] + a1[2]) * inv + sa.z;  h[3] = (a0[3] + a1[3]) * inv + sa.w;
    h[4] = (a0[4] + a1[4]) * inv + sb2.x; h[5] = (a0[5] + a1[5]) * inv + sb2.y;
    h[6] = (a0[6] + a1[6]) * inv + sb2.z; h[7] = (a0[7] + a1[7]) * inv + sb2.w;
#pragma unroll
    for (int j = 0; j < 8; j++) h[j] = h[j] > 0.0f ? h[j] : 0.0f;

    if (!LAYER2) {
        *(float4*)(h1o + (size_t)dst * D + 8 * c)     = make_float4(h[0], h[1], h[2], h[3]);
        *(float4*)(h1o + (size_t)dst * D + 8 * c + 4) = make_float4(h[4], h[5], h[6], h[7]);
    } else {
        float p0 = 0.f, p1 = 0.f;
#pragma unroll
        for (int j = 0; j < 8; j++) {
            p0 += h[j] * woF[(8 * c + j) * 2 + 0];
            p1 += h[j] * woF[(8 * c + j) * 2 + 1];
        }
#pragma unroll
        for (int m = LPD / 2; m >= 1; m >>= 1) {
            p0 += __shfl_xor(p0, m, LPD);
            p1 += __shfl_xor(p1, m, LPD);
        }
        if (c == 0) {
            float o0 = p0 + woF[32];
            float o1 = p1 + woF[33];
            if (flags[0]) {
                ((bf16*)out)[dst * 2 + 0] = __float2bfloat16(o0);
                ((bf16*)out)[dst * 2 + 1] = __float2bfloat16(o1);
            } else {
                ((float*)out)[dst * 2 + 0] = o0;
                ((float*)out)[dst * 2 + 1] = o1;
            }
        }
    }
}

extern "C" void kernel_launch(void* const* d_in, const int* in_sizes, int n_in,
                              void* d_out, int out_size, void* d_ws, size_t ws_size,
                              hipStream_t stream) {
    const int* ei  = (const int*)d_in[0];
    const void* emb = d_in[1];
    const void *Wq1 = d_in[2],  *bq1 = d_in[3];
    const void *Wk1 = d_in[4],  *bk1 = d_in[5];
    const void *Wv1 = d_in[6],  *bv1 = d_in[7];
    const void *Ws1 = d_in[8],  *bs1 = d_in[9];
    const void *Wq2 = d_in[10], *bq2 = d_in[11];
    const void *Wk2 = d_in[12], *bk2 = d_in[13];
    const void *Wv2 = d_in[14], *bv2 = d_in[15];
    const void *Ws2 = d_in[16], *bs2 = d_in[17];
    const void *Wo  = d_in[18], *bo  = d_in[19];

    // Workspace layout (floats). pairsSB aliases q (dead after radix_b).
    const size_t ND = (size_t)N_NODES * 32;
    const size_t SBTOT = (size_t)NSB * SBCAP;      // 2,007,040
    float* base   = (float*)d_ws;
    int*   flags  = (int*)base;                    // 64
    float* wp1    = base + 64;                     // 4096
    float* bp1    = wp1 + 4096;                    // 128
    float* wp2    = bp1 + 128;                     // 2048
    float* bp2    = wp2 + 2048;                    // 64
    float* woF    = bp2 + 64;                      // 64
    int*   curSB  = (int*)(woF + 64);              // 256
    int*   cnt    = curSB + 256;                   // CNT_N (12544) -> pad 12800
    int*   rowbeg = cnt + 12800;                   // N_NODES
    int*   rowend = rowbeg + N_NODES;              // N_NODES
    int*   perm   = rowend + N_NODES;              // N_NODES
    float* uni    = (float*)(perm + N_NODES);      // union start
    uint*  pairsSB = (uint*)uni;                   // SBTOT uints (8 MB, alias q)
    float* q      = uni;                           // ND
    float* s      = uni + ND;                      // ND
    ushort* kvb   = (ushort*)(uni + 2 * ND);       // 2*ND ushorts = ND floats
    float* h1     = uni + 3 * ND;                  // ND
    int*   esrc   = (int*)(uni + 4 * ND);          // SBTOT ints (8 MB)
    // total ~ 62 MB

    const int B = 256;
    const int gNL32   = (N_NODES + 31) / 32;           // 3125 (NPB=32)
    const int gNL16   = (N_NODES + 63) / 64;           // 1563 (NPB=64)
    const int gGat32  = ((N_NODES + 15) / 16 * 64 + B - 1) / B;  // G=16 -> 1563
    const int gGat16  = ((N_NODES + 31) / 32 * 64 + B - 1) / B;  // G=32 -> 782
    const int gRadA   = (N_EDGES_C + RND - 1) / RND;   // 782

    // 1: setup (detect + cast params + zero curSB)
    setup_kernel<<<1, B, 0, stream>>>(emb, ei,
        Wq1, bq1, Wk1, bk1, Wv1, bv1, Ws1, bs1,
        Wq2, bq2, Wk2, bk2, Wv2, bv2, Ws2, bs2, Wo, bo,
        flags, wp1, bp1, wp2, bp2, woF, curSB);

    // 2-3: CSR build via LDS-coalesced 2-level radix (+ fused degree histogram)
    radix_a<<<gRadA, B, 0, stream>>>(ei, flags, curSB, pairsSB);
    radix_b<<<NSB, 512, 0, stream>>>(curSB, pairsSB, esrc, rowbeg, rowend, cnt);

    // 4-5: degree-sorted dst permutation (single-block scan + LDS-rank scatter)
    scan_all<<<1, 1024, 0, stream>>>(cnt);
    perm_scatter3<<<NSB, 512, 0, stream>>>(rowbeg, rowend, cnt, perm);

    // 6-7: Layer 1 (32 -> 32)
    node_linear<32, true><<<gNL32, B, 0, stream>>>(emb, wp1, bp1, flags, q, kvb, s);
    gather_attn<32, false><<<gGat32, B, 0, stream>>>(
        perm, rowbeg, rowend, esrc, q, kvb, s, woF, flags, h1, nullptr);

    // 8-9: Layer 2 (32 -> 16) + output linear
    node_linear<16, false><<<gNL16, B, 0, stream>>>(h1, wp2, bp2, flags, q, kvb, s);
    gather_attn<16, true><<<gGat16, B, 0, stream>>>(
        perm, rowbeg, rowend, esrc, q, kvb, s, woF, flags, nullptr, d_out);
}